// Round 7
// baseline (4805.713 us; speedup 1.0000x reference)
//
#include <hip/hip_runtime.h>

#define H_ 384
#define W_ 512
#define N_ (H_*W_)        // 196608
#define B_ 2
#define T_ 1048576
#define TMASK_ 0xFFFFFu
#define G2N_ ((2*N_)/256) // 1536
#define G2T_ ((2*T_)/256) // 8192
#define CHS_ 64           // doubles per channel accumulator block (8 subs x 8-double spacing)
// scalD layout (doubles), all accumulators 8-way sub-slot spread (64B apart):
//   [0..191]   zeroD (stays 0)
//   rz  [b][it] at 192   + b*2688 + it*192   (it=0..13)
//   pAp [b][it] at 5568  + b*2496 + it*192   (it=0..12)
//   GN acc      at 10560 + L*512 + bg*128 (+j*8 sum, +64+j*8 sumsq)
#define RZ0_ 192
#define RZB_ 2688
#define PAP0_ 5568
#define PAPB_ 2496
#define GN0_ 10560

__device__ __forceinline__ int prime(int d){
  switch(d){
    case 0: return 73856093;
    case 1: return 19349663;
    case 2: return 83492791;
    case 3: return 49979687;
    default: return 24036583;
  }
}

__device__ __forceinline__ float clampScale(float s){ return fminf(fmaxf(s,1e-5f),1.0f); }

__device__ __forceinline__ double blockReduceD(double v){
  __shared__ double sh[4];
  for(int s=32;s>0;s>>=1) v += __shfl_down(v,s,64);
  int lane=threadIdx.x&63, w=threadIdx.x>>6;
  if(lane==0) sh[w]=v;
  __syncthreads();
  double r = sh[0]+sh[1]+sh[2]+sh[3];
  __syncthreads();
  return r;
}
__device__ __forceinline__ float blockReduceMaxF(float v){
  __shared__ float sh[4];
  for(int s=32;s>0;s>>=1) v = fmaxf(v,__shfl_down(v,s,64));
  int lane=threadIdx.x&63, w=threadIdx.x>>6;
  if(lane==0) sh[w]=v;
  __syncthreads();
  float r = fmaxf(fmaxf(sh[0],sh[1]),fmaxf(sh[2],sh[3]));
  __syncthreads();
  return r;
}

// spread atomic into 8 sub-slots (separate 64B lines); consumer sums 8
__device__ __forceinline__ void redAdd(double* base, int c, double v){
  atomicAdd(&base[c*CHS_ + ((blockIdx.x&7)<<3)], v);
}
__device__ __forceinline__ float redSum(const double* base, int c){
  double s=0.0;
  #pragma unroll
  for(int j=0;j<8;j++) s += base[c*CHS_ + j*8];
  return (float)s;
}

// GN stats from the 8-way-spread double accumulator -> float mean/rstd
__device__ __forceinline__ void gnStats(const double* acc, int b, int c, double len,
                                        float* mf, float* rs){
  const double* ba = acc + (b*2 + (c>>3))*128;
  double s=0.0,s2=0.0;
  #pragma unroll
  for(int j=0;j<8;j++){ s+=ba[j*8]; s2+=ba[64+j*8]; }
  double mean = s/len;
  double var = s2/len - mean*mean;
  *rs = (float)(1.0/sqrt(var + 1e-5));
  *mf = (float)mean;
}

// ---------------- CNN kernels ----------------

__global__ __launch_bounds__(256) void k_maxes(const float4* img4, const float4* feat4, float* scal){
  const int PB = (3*N_)/4;
  for(int b=0;b<2;b++){
    float lm=0.f, lf=0.f;
    for(int idx = blockIdx.x*256+threadIdx.x; idx<PB; idx += gridDim.x*256){
      float4 a=img4[(size_t)b*PB+idx], c=feat4[(size_t)b*PB+idx];
      lm=fmaxf(lm, fmaxf(fmaxf(a.x,a.y),fmaxf(a.z,a.w)));
      lf=fmaxf(lf, fmaxf(fmaxf(c.x,c.y),fmaxf(c.z,c.w)));
    }
    lm=blockReduceMaxF(lm); lf=blockReduceMaxF(lf);
    if(threadIdx.x==0){
      atomicMax((int*)&scal[b],   __float_as_int(lm));
      atomicMax((int*)&scal[2+b], __float_as_int(lf));
    }
  }
}

// GN+relu applied elementwise once; stats once per block (blocks never span (b,c))
template<int PLANE4>
__global__ __launch_bounds__(256) void k_gnrelu(const float4* in, float4* out, const double* acc,
                                                const float* gamma, const float* beta){
  int idx = blockIdx.x*256 + threadIdx.x;   // grid exactly B*16*PLANE4/256
  int t = idx / PLANE4;
  int c = t & 15, b = t >> 4;
  __shared__ float smf, srs, sg, sbe;
  if(threadIdx.x==0){
    float mf, rs;
    gnStats(acc, b, c, 8.0*(double)(PLANE4*4), &mf, &rs);
    smf=mf; srs=rs; sg=gamma[c]; sbe=beta[c];
  }
  __syncthreads();
  float mf=smf, rs=srs, g=sg, be=sbe;
  float4 v = in[idx];
  v.x = fmaxf((v.x-mf)*rs*g+be, 0.f);
  v.y = fmaxf((v.y-mf)*rs*g+be, 0.f);
  v.z = fmaxf((v.z-mf)*rs*g+be, 0.f);
  v.w = fmaxf((v.w-mf)*rs*g+be, 0.f);
  out[idx] = v;
}

template<bool SCALEA,int NCH,int K,int S,bool EDGE,int IH,int IW,int NOC>
__device__ __forceinline__ void conv_accum(const float* __restrict__ plane0, int icBase, float sA,
                                           int oy, int ox, const float* wlds, float acc[NOC]){
  for(int ic=0; ic<NCH; ic++){
    const float* plane = plane0 + (size_t)ic*IH*IW;
    #pragma unroll
    for(int ky=0;ky<K;ky++){
      int iy = oy*S + ky - 1;
      int cy = min(max(iy,0),IH-1);
      bool yin = (iy>=0)&&(iy<IH);
      const float* row = plane + cy*IW;
      #pragma unroll
      for(int kx=0;kx<K;kx++){
        int ix = ox*S + kx - 1;
        float v;
        if(EDGE){
          int cx = min(max(ix,0),IW-1);
          v = row[cx];
          if(SCALEA) v = v / sA;
        } else {
          bool inb = yin && ix>=0 && ix<IW;
          if(inb){
            v = row[ix];
            if(SCALEA) v = v / sA;
          } else v = 0.f;
        }
        const float* wp = &wlds[((icBase+ic)*K*K + ky*K + kx)*NOC];
        #pragma unroll
        for(int q=0;q<NOC;q++) acc[q] += v*wp[q];
      }
    }
  }
}

// OCSPLIT: grid = OCSPLIT * (B*OH*OW/256); each thread computes 16/OCSPLIT output channels.
template<bool SCALEA,int ICA,int ICB,int K,int S,bool EDGE,int IH,int IW,int OH,int OW,int OCSPLIT>
__global__ __launch_bounds__(256) void k_convT(const float* __restrict__ inA, const float* __restrict__ inB,
                        const float* __restrict__ wt, const float* __restrict__ bias,
                        float* __restrict__ out, double* gnaccOut, const float* scal){
  constexpr int IC = ICA+ICB;
  constexpr int NOC = 16/OCSPLIT;
  constexpr int PB = (B_*OH*OW)/256;
  __shared__ float wlds[IC*K*K*NOC];
  __shared__ float blds[NOC];
  int pb  = blockIdx.x % PB;
  int ocg = blockIdx.x / PB;
  int ocBase = ocg*NOC;
  for(int i=threadIdx.x; i<IC*K*K*NOC; i+=256){
    int q = i % NOC, ickk = i / NOC;
    wlds[i] = wt[(ocBase+q)*IC*K*K + ickk];
  }
  if(threadIdx.x<NOC) blds[threadIdx.x]=bias[ocBase+threadIdx.x];
  __syncthreads();
  int idx = pb*256+threadIdx.x;
  int ox = idx % OW; int t=idx/OW; int oy=t%OH; int b=t/OH;   // blocks never span batches
  float sA = SCALEA ? clampScale(scal[b]) : 1.0f;
  float acc[NOC];
  #pragma unroll
  for(int q=0;q<NOC;q++) acc[q]=0.f;
  conv_accum<SCALEA,ICA,K,S,EDGE,IH,IW,NOC>(inA + (size_t)b*ICA*IH*IW, 0, sA, oy, ox, wlds, acc);
  if constexpr(ICB>0)
    conv_accum<false,(ICB>0?ICB:1),K,S,EDGE,IH,IW,NOC>(inB + (size_t)b*ICB*IH*IW, ICA, 1.0f, oy, ox, wlds, acc);
  double s=0.0,s2=0.0;
  #pragma unroll
  for(int q=0;q<NOC;q++){
    float vv = acc[q] + blds[q];
    out[(((size_t)b*16+(ocBase+q))*OH+oy)*OW+ox] = vv;
    s += vv; s2 += (double)vv*(double)vv;
  }
  s=blockReduceD(s); s2=blockReduceD(s2);
  if(threadIdx.x==0){
    int grp = ocBase>>3;                 // NOC<=8: all of a thread's channels in one GN group
    int sub = (blockIdx.x&7)<<3;
    atomicAdd(&gnaccOut[(b*2+grp)*128 + sub],      s);
    atomicAdd(&gnaccOut[(b*2+grp)*128 + 64 + sub], s2);
  }
}

// Specialized GN(+relu) + exact 2x half-pixel bilinear upsample.
template<int IH,int IW>
__global__ __launch_bounds__(256) void k_resize2x(const float* __restrict__ in, float* __restrict__ out,
                                                  const double* acc, const float* gamma, const float* beta){
  constexpr int QP = IH*IW;     // quads per plane
  constexpr int OW = 2*IW;
  int idx = blockIdx.x*256 + threadIdx.x;   // grid exactly B*16*QP/256
  int q = idx % QP; int t = idx / QP;       // t = b*16+c
  int qx = q % IW, qy = q / IW;
  int c = t & 15, b = t >> 4;
  __shared__ float smf, srs, sg, sbe;
  if(threadIdx.x==0){
    float mf, rs;
    gnStats(acc, b, c, 8.0*(double)QP, &mf, &rs);
    smf=mf; srs=rs; sg=gamma[c]; sbe=beta[c];
  }
  __syncthreads();
  float mf=smf, rs=srs, g=sg, be=sbe;
  const float* plane = in + (size_t)t*QP;
  int ym = max(qy-1,0), yp = min(qy+1,IH-1);
  int xm = max(qx-1,0), xp = min(qx+1,IW-1);
  const float* r0 = plane + ym*IW;
  const float* r1 = plane + qy*IW;
  const float* r2 = plane + yp*IW;
  float a00=fmaxf((r0[xm]-mf)*rs*g+be,0.f), a01=fmaxf((r0[qx]-mf)*rs*g+be,0.f), a02=fmaxf((r0[xp]-mf)*rs*g+be,0.f);
  float a10=fmaxf((r1[xm]-mf)*rs*g+be,0.f), a11=fmaxf((r1[qx]-mf)*rs*g+be,0.f), a12=fmaxf((r1[xp]-mf)*rs*g+be,0.f);
  float a20=fmaxf((r2[xm]-mf)*rs*g+be,0.f), a21=fmaxf((r2[qx]-mf)*rs*g+be,0.f), a22=fmaxf((r2[xp]-mf)*rs*g+be,0.f);
  float e0 = 0.25f*a00+0.75f*a01, o0 = 0.75f*a01+0.25f*a02;
  float e1 = 0.25f*a10+0.75f*a11, o1 = 0.75f*a11+0.25f*a12;
  float e2 = 0.25f*a20+0.75f*a21, o2 = 0.75f*a21+0.25f*a22;
  float2 rE = make_float2(0.25f*e0+0.75f*e1, 0.25f*o0+0.75f*o1);
  float2 rO = make_float2(0.75f*e1+0.25f*e2, 0.75f*o1+0.25f*o2);
  float* po = out + (size_t)t*(4*QP) + (size_t)(2*qy)*OW + 2*qx;
  *(float2*)po        = rE;
  *(float2*)(po + OW) = rO;
}

// conf head: TWO y-adjacent pixels per thread (shares input rows)
__global__ __launch_bounds__(256) void k_conv5(const float* in, const float* wf, const float* bf,
                                               float* confr, float* scal){
  int idx = blockIdx.x*256 + threadIdx.x;   // grid exactly B*(N/2)/256
  int ph = idx % (N_/2); int b = idx / (N_/2);
  int oyh = ph / W_, ox = ph % W_;
  int oy0 = oyh*2;
  float acc0 = bf[0], acc1 = bf[0];
  for(int ic=0; ic<16; ic++){
    const float* plane = in + ((size_t)b*16+ic)*N_;
    #pragma unroll
    for(int ky=0;ky<3;ky++){
      int iy0 = min(max(oy0+ky-1,0),H_-1);
      int iy1 = min(max(oy0+ky,0),H_-1);
      const float* row0 = plane + iy0*W_;
      const float* row1 = plane + iy1*W_;
      #pragma unroll
      for(int kx=0;kx<3;kx++){
        int ix = min(max(ox+kx-1,0),W_-1);
        float w = wf[(ic*3+ky)*3+kx];
        acc0 += row0[ix]*w;
        acc1 += row1[ix]*w;
      }
    }
  }
  float c0 = 0.5f*(tanhf(acc0)+1.0f);
  float c1 = 0.5f*(tanhf(acc1)+1.0f);
  confr[(size_t)b*N_ + oy0*W_ + ox]     = c0;
  confr[(size_t)b*N_ + (oy0+1)*W_ + ox] = c1;
  float mx = blockReduceMaxF(fmaxf(c0,c1));
  if(threadIdx.x==0) atomicMax((int*)&scal[4], __float_as_int(mx));
}

// ---------------- bilateral solver setup (both batches merged) ----------------

__global__ __launch_bounds__(256) void k_px1(const float* feat, const float* scal,
                                             int* hpix, int2* cpix2, int* winner){
  int idx = blockIdx.x*256 + threadIdx.x;   // grid exactly 2N/256
  int b = idx / N_, pix = idx % N_;
  int y = pix / W_, x = pix % W_;
  float sF = clampScale(scal[2+b]);
  const float* fb = feat + (size_t)b*3*N_;
  // exact reference eval order, no FMA contraction (coords are integer-binned)
  float R  = __fmul_rn(__fdiv_rn(fb[pix],      sF), 255.0f);
  float G  = __fmul_rn(__fdiv_rn(fb[N_+pix],   sF), 255.0f);
  float Bl = __fmul_rn(__fdiv_rn(fb[2*N_+pix], sF), 255.0f);
  float Y = __fadd_rn(__fadd_rn(__fadd_rn(__fmul_rn(0.299f,R),     __fmul_rn(0.587f,G)),  __fmul_rn(0.114f,Bl)), 0.0f);
  float U = __fadd_rn(__fadd_rn(__fadd_rn(__fmul_rn(-0.168736f,R), __fmul_rn(-0.331264f,G)), __fmul_rn(0.5f,Bl)), 128.0f);
  float V = __fadd_rn(__fadd_rn(__fadd_rn(__fmul_rn(0.5f,R),       __fmul_rn(-0.418688f,G)), __fmul_rn(-0.081312f,Bl)), 128.0f);
  int c[5];
  c[0] = (int)floorf(__fdiv_rn((float)x, 7.0f));
  c[1] = (int)floorf(__fdiv_rn((float)y, 7.0f));
  c[2] = (int)floorf(__fdiv_rn(Y, 8.0f));
  c[3] = (int)floorf(__fdiv_rn(U, 2.0f));
  c[4] = (int)floorf(__fdiv_rn(V, 2.0f));
  unsigned hh = 0;
  #pragma unroll
  for(int d=0;d<5;d++) hh += (unsigned)c[d]*(unsigned)prime(d);
  hh &= TMASK_;
  hpix[idx]=(int)hh;
  cpix2[idx]=make_int2(c[0] | (c[1]<<10) | (c[2]<<20), c[3] | (c[4]<<10));
  atomicMax(&winner[(size_t)b*T_+(int)hh], pix);   // last-writer (max pix) wins = XLA scatter
}

// atomic compaction: replaces cnt+scan(serial)+cmp (3 kernels) and the cidx2 memset.
// gi order is nondeterministic, but all downstream structures are index-based;
// only fp reduction order shifts (<< bf16 output quantization).
__global__ __launch_bounds__(256) void k_cmpA(const int* winner, int* count,
                                              int2* cidx2, int* slot_of){
  int t = blockIdx.x*256 + threadIdx.x;   // grid exactly 2T/256
  int b = t / T_;
  int wn = winner[t];
  if(wn >= 0){
    int li = atomicAdd(&count[b], 1);     // wave-aggregated by compiler
    int gi = b*N_ + li;
    cidx2[t] = make_int2(gi, wn);
    slot_of[gi] = t - b*T_;               // local slot hh
  } else {
    cidx2[t] = make_int2(-1, -1);         // unoccupied marker (.y<0)
  }
}

// conf normalize + splat: winner plain-stores; non-winners (~10%) atomicAdd into extras
__global__ __launch_bounds__(256) void k_px3(int* hpix_gpix, const int2* cidx2, const float* confr,
                                             const float* scal, float* confout, const float* pred,
                                             float* mcomp, float4* splat4, float* mcompE, float* splatE){
  int idx = blockIdx.x*256 + threadIdx.x;   // grid exactly 2N/256
  int b = idx / N_, pix = idx % N_;
  int2 cw = cidx2[(size_t)b*T_ + hpix_gpix[idx]];
  int gi = cw.x;
  hpix_gpix[idx] = gi;
  float w = confr[idx] / fmaxf(scal[4], 1e-5f);
  confout[idx] = w;
  const float* pb = pred + (size_t)b*3*N_;
  float v0 = __fmul_rn(w, pb[pix]);
  float v1 = __fmul_rn(w, pb[N_+pix]);
  float v2 = __fmul_rn(w, pb[2*N_+pix]);
  if(cw.y == pix){
    splat4[gi] = make_float4(v0,v1,v2,w);
    mcomp[gi] = 1.0f;
  } else {
    float* s = splatE + 4*(size_t)gi;
    atomicAdd(s+0, v0);
    atomicAdd(s+1, v1);
    atomicAdd(s+2, v2);
    atomicAdd(s+3, w);
    atomicAdd(&mcompE[gi], 1.0f);
  }
}

// ---------------- solver kernels (proven r5 CG path) ----------------
// CG state packing: zp[2i] = {z0,z1,z2,mi}, zp[2i+1] = {p0,p1,p2,nv} — one 64B line
// per neighbor gather in k_Ap.

// fused: merge extras + neighbor-table build + first bisto iter (n0=1)
__global__ __launch_bounds__(256) void k_bisto0(const int* count, const int* slot_of,
                      const int2* cpix2, const int2* cidx2, int* nbr,
                      float* mcomp, const float* mcompE, float4* splat4, const float4* splatE4,
                      float* nd){
  int i = blockIdx.x*256 + threadIdx.x;     // grid exactly 2N/256
  int b = i / N_, li = i - b*N_;
  if(li >= count[b]) return;
  int hh = slot_of[i];
  const int2* c2b = cidx2 + (size_t)b*T_;
  int2 cself = c2b[hh];
  int2 cp = cpix2[(size_t)b*N_ + cself.y];
  float4 sp = splat4[i]; float4 se = splatE4[i];
  sp.x+=se.x; sp.y+=se.y; sp.z+=se.z; sp.w+=se.w;
  splat4[i]=sp;
  float mTot = mcomp[i] + mcompE[i];
  mcomp[i]=mTot;
  float bv = 10.f;
  #pragma unroll
  for(int j=0;j<10;j++){
    int d=j>>1; int off=(j&1)?1:-1;
    unsigned nh = ((unsigned)hh + (unsigned)(off*prime(d))) & TMASK_;
    int nb = -1;
    int2 cn2 = c2b[nh];
    if(cn2.y>=0){
      int2 cn = cpix2[(size_t)b*N_ + cn2.y];
      int e0 = cp.x + (d==0?off: d==1?off*(1<<10) : d==2?off*(1<<20) : 0);
      int e1 = cp.y + (d==3?off: d==4?off*(1<<10) : 0);
      if(cn.x==e0 && cn.y==e1) nb = cn2.x;
    }
    nbr[(size_t)j*(2*N_)+i]=nb;
    if(nb>=0) bv += 1.0f;
  }
  nd[i] = sqrtf(1.0f*mTot/(bv+1e-12f));
}

__global__ __launch_bounds__(256) void k_bisto(const int* count, const int* nbr,
                                               const float* ns, float* nd, const float* mc){
  int i = blockIdx.x*256 + threadIdx.x;
  int b = i / N_, li = i - b*N_;
  if(li >= count[b]) return;
  float nv = ns[i];
  float bv = 10.f*nv;
  #pragma unroll
  for(int j=0;j<10;j++){
    int nb = nbr[(size_t)j*(2*N_)+i];
    if(nb>=0) bv += ns[nb];
  }
  nd[i] = sqrtf(nv*mc[i]/(bv+1e-12f));
}

// fused mfinal + x0 + A(x0) + r0/z0/p0 + rz0 per-batch reduction
__global__ __launch_bounds__(256) void k_Ar0(const int* count, const int* nbr, const float* n,
                      const float4* splat4, float4* meta4, float4* x4, float4* rS, float4* zp0,
                      double* rz0){
  int i = blockIdx.x*256 + threadIdx.x;
  int b = i / N_, li = i - b*N_;
  double a0=0.0,a1=0.0,a2=0.0;
  if(li < count[b]){
    float4 vb4 = splat4[i];
    float wsi = vb4.w;
    float nv = n[i];
    float x0 = vb4.x/(wsi+1e-12f);
    float x1 = vb4.y/(wsi+1e-12f);
    float x2 = vb4.z/(wsi+1e-12f);
    float bv = 10.f*nv;
    float s0=10.f*(nv*x0), s1=10.f*(nv*x1), s2=10.f*(nv*x2);
    #pragma unroll
    for(int j=0;j<10;j++){
      int nb = nbr[(size_t)j*(2*N_)+i];
      if(nb>=0){
        float4 vbn = splat4[nb];
        float nn = n[nb];
        bv += nn;
        s0 += nn*(vbn.x/(vbn.w+1e-12f));
        s1 += nn*(vbn.y/(vbn.w+1e-12f));
        s2 += nn*(vbn.z/(vbn.w+1e-12f));
      }
    }
    float mfin = nv*bv;
    float Ad = fmaxf(200.0f*(mfin - 10.f*nv*nv) + wsi, 1e-5f);
    float mi = 1.0f/Ad;
    float A0 = 200.f*(mfin*x0 - nv*s0) + wsi*x0;
    float A1 = 200.f*(mfin*x1 - nv*s1) + wsi*x1;
    float A2 = 200.f*(mfin*x2 - nv*s2) + wsi*x2;
    float r0v = vb4.x-A0, r1v = vb4.y-A1, r2v = vb4.z-A2;
    float z0=mi*r0v, z1=mi*r1v, z2=mi*r2v;
    meta4[i]=make_float4(nv,mfin,wsi,mi);
    x4[i]=make_float4(x0,x1,x2,0.f);
    rS[i]=make_float4(r0v,r1v,r2v,mi);
    zp0[2*(size_t)i]   = make_float4(z0,z1,z2,mi);
    zp0[2*(size_t)i+1] = make_float4(z0,z1,z2,nv);   // p0 = z0
    a0=(double)r0v*z0; a1=(double)r1v*z1; a2=(double)r2v*z2;
  }
  a0=blockReduceD(a0); a1=blockReduceD(a1); a2=blockReduceD(a2);
  if(threadIdx.x==0){
    double* base = rz0 + b*RZB_;
    redAdd(base,0,a0); redAdd(base,1,a1); redAdd(base,2,a2);
  }
}

// fused p-update + A: p = z + beta*pOld; gathers one 64B {z,p} line per neighbor.
// beta computed once per block (thread 0).
__global__ __launch_bounds__(256) void k_Ap(const int* count, const int* nbr, const float4* meta4,
                     const float4* __restrict__ zpCur, float4* __restrict__ zpNext, float4* Ap4,
                     const double* bNum, const double* bDen, int bstr, double* pAp){
  int i = blockIdx.x*256 + threadIdx.x;
  int b = (blockIdx.x*256) / N_;      // blocks never span batches
  int li = i - b*N_;
  __shared__ float sbe[3];
  if(threadIdx.x==0){
    if(bstr==0){ sbe[0]=0.f; sbe[1]=0.f; sbe[2]=0.f; }
    else{
      const double* nB_ = bNum + b*bstr;
      const double* dB_ = bDen + b*bstr;
      #pragma unroll
      for(int c=0;c<3;c++) sbe[c] = redSum(nB_,c) / (redSum(dB_,c)+1e-12f);
    }
  }
  __syncthreads();
  float be0=sbe[0], be1=sbe[1], be2=sbe[2];
  double a0=0.0,a1=0.0,a2=0.0;
  if(li < count[b]){
    float4 mt = meta4[i];
    float nv = mt.x, mfin = mt.y, wsi = mt.z;
    float4 zs = zpCur[2*(size_t)i];
    float4 ps = zpCur[2*(size_t)i+1];
    float p0 = zs.x + be0*ps.x;
    float p1 = zs.y + be1*ps.y;
    float p2 = zs.z + be2*ps.z;
    float s0=10.f*(nv*p0), s1=10.f*(nv*p1), s2=10.f*(nv*p2);
    #pragma unroll
    for(int j=0;j<10;j++){
      int nb = nbr[(size_t)j*(2*N_)+i];
      if(nb>=0){
        float4 zn = zpCur[2*(size_t)nb];
        float4 pn = zpCur[2*(size_t)nb+1];
        float nn = pn.w;
        s0 += nn*(zn.x + be0*pn.x);
        s1 += nn*(zn.y + be1*pn.y);
        s2 += nn*(zn.z + be2*pn.z);
      }
    }
    float A0 = 200.f*(mfin*p0 - nv*s0) + wsi*p0;
    float A1 = 200.f*(mfin*p1 - nv*s1) + wsi*p1;
    float A2 = 200.f*(mfin*p2 - nv*s2) + wsi*p2;
    zpNext[2*(size_t)i+1]=make_float4(p0,p1,p2,nv);
    Ap4[i]=make_float4(A0,A1,A2,0.f);
    a0=(double)p0*A0; a1=(double)p1*A1; a2=(double)p2*A2;
  }
  a0=blockReduceD(a0); a1=blockReduceD(a1); a2=blockReduceD(a2);
  if(threadIdx.x==0){
    double* base = pAp + b*PAPB_;
    redAdd(base,0,a0); redAdd(base,1,a1); redAdd(base,2,a2);
  }
}

// x/r update + z for next iter; alpha computed once per block (thread 0)
__global__ __launch_bounds__(256) void k_upd1(const int* count, float4* x4, float4* rS,
                       const float4* __restrict__ zpNext_p, float4* __restrict__ zpNext_z,
                       const float4* Ap4,
                       const double* rzCur, const double* pApC, double* rzNew, int doRz){
  int i = blockIdx.x*256 + threadIdx.x;
  int b = (blockIdx.x*256) / N_;
  int li = i - b*N_;
  __shared__ float sal[3];
  if(threadIdx.x==0){
    const double* rc = rzCur + b*RZB_;
    const double* pc = pApC  + b*PAPB_;
    #pragma unroll
    for(int c=0;c<3;c++) sal[c] = redSum(rc,c) / (redSum(pc,c)+1e-12f);
  }
  __syncthreads();
  float al0=sal[0], al1=sal[1], al2=sal[2];
  double a0=0.0,a1=0.0,a2=0.0;
  if(li < count[b]){
    float4 xv = x4[i];
    float4 rv = rS[i];
    float4 pv = zpNext_p[2*(size_t)i+1];
    float4 av = Ap4[i];
    float mi = rv.w;
    float x0=xv.x+al0*pv.x, x1=xv.y+al1*pv.y, x2=xv.z+al2*pv.z;
    float r0v=rv.x-al0*av.x, r1v=rv.y-al1*av.y, r2v=rv.z-al2*av.z;
    float z0=mi*r0v, z1=mi*r1v, z2=mi*r2v;
    x4[i]=make_float4(x0,x1,x2,0.f);
    rS[i]=make_float4(r0v,r1v,r2v,mi);
    zpNext_z[2*(size_t)i]=make_float4(z0,z1,z2,mi);
    a0=(double)r0v*z0; a1=(double)r1v*z1; a2=(double)r2v*z2;
  }
  if(doRz){
    a0=blockReduceD(a0); a1=blockReduceD(a1); a2=blockReduceD(a2);
    if(threadIdx.x==0){
      double* base = rzNew + b*RZB_;
      redAdd(base,0,a0); redAdd(base,1,a1); redAdd(base,2,a2);
    }
  }
}

__global__ __launch_bounds__(256) void k_out(const float4* x4, const int* gpix, float* out){
  int idx = blockIdx.x*256 + threadIdx.x;   // grid exactly 2N/256
  int b = idx / N_, pix = idx % N_;
  float4 xv = x4[gpix[idx]];
  out[((size_t)(b*3+0))*N_+pix] = xv.x;
  out[((size_t)(b*3+1))*N_+pix] = xv.y;
  out[((size_t)(b*3+2))*N_+pix] = xv.z;
}

// ---------------- host launcher ----------------

extern "C" void kernel_launch(void* const* d_in, const int* in_sizes, int n_in,
                              void* d_out, int out_size, void* d_ws, size_t ws_size,
                              hipStream_t stream){
  const float* image=(const float*)d_in[0];
  const float* feature=(const float*)d_in[1];
  const float* pred=(const float*)d_in[2];
  const float* w1=(const float*)d_in[3];  const float* b1=(const float*)d_in[4];
  const float* g1=(const float*)d_in[5];  const float* be1=(const float*)d_in[6];
  const float* w2=(const float*)d_in[7];  const float* b2=(const float*)d_in[8];
  const float* g2=(const float*)d_in[9];  const float* be2=(const float*)d_in[10];
  const float* wd1=(const float*)d_in[11];const float* bd1=(const float*)d_in[12];
  const float* gd1=(const float*)d_in[13];const float* bed1=(const float*)d_in[14];
  const float* wd2=(const float*)d_in[15];const float* bd2=(const float*)d_in[16];
  const float* gd2=(const float*)d_in[17];const float* bed2=(const float*)d_in[18];
  const float* wf=(const float*)d_in[19]; const float* bf=(const float*)d_in[20];
  float* outp=(float*)d_out;                          // (B,3,H,W)
  float* confout = outp + (size_t)B_*3*N_;            // (B,1,H,W)

  char* wsb=(char*)d_ws;
  float* scal=(float*)wsb;                  // [0..1] imgmax, [2..3] featmax, [4] confmax
  int* count=(int*)(wsb+256);               // count[2]
  double* scalD=(double*)(wsb+4096);        // 12608 doubles (see layout defines)
  double* zeroD = scalD;
  auto rzArr  = [&](int it)->double*{ return scalD + RZ0_  + it*192; };   // batch stride RZB_
  auto pApArr = [&](int it)->double*{ return scalD + PAP0_ + it*192; };   // batch stride PAPB_
  auto gnAcc  = [&](int L)->double*{ return scalD + GN0_ + L*512; };

  size_t off = 131072;
  auto alloc=[&](size_t bytes)->char*{ char* pp=wsb+off; off=(off+bytes+255)&~(size_t)255; return pp; };
  const size_t ALLOC0 = off;

  // CNN region (dead once conf is in confr; bilateral region overlaps it)
  float* x1   =(float*)alloc((size_t)B_*16*192*256*4);
  float* x1n  =(float*)alloc((size_t)B_*16*192*256*4);
  float* x2   =(float*)alloc((size_t)B_*16*96*128*4);
  float* x2n  =(float*)alloc((size_t)B_*16*96*128*4);
  float* dx1  =(float*)alloc((size_t)B_*16*96*128*4);
  float* dx1r =(float*)alloc((size_t)B_*16*192*256*4);
  float* dx2  =(float*)alloc((size_t)B_*16*192*256*4);
  float* dx2r =(float*)alloc((size_t)B_*16*N_*4);

  // bilateral region (reset offset: CNN buffers dead before the solver memsets/writes)
  off = ALLOC0;
  int*    winner =(int*)   alloc((size_t)2*T_*4);
  int2*   cidx2  =(int2*)  alloc((size_t)2*T_*8);
  int*    hpix   =(int*)   alloc((size_t)2*N_*4);    // becomes gpix after k_px3
  int2*   cpix2  =(int2*)  alloc((size_t)2*N_*8);
  int*    slot_of=(int*)   alloc((size_t)2*N_*4);
  int*    nbr    =(int*)   alloc((size_t)2*N_*10*4);
  float*  mcomp  =(float*) alloc((size_t)2*N_*4);    // mcomp..splatE contiguous: one memset
  float4* splat4 =(float4*)alloc((size_t)2*N_*16);
  float*  mcompE =(float*) alloc((size_t)2*N_*4);
  float*  splatE =(float*) alloc((size_t)2*N_*16);
  float*  nA     =(float*) alloc((size_t)2*N_*4);
  float*  nB     =(float*) alloc((size_t)2*N_*4);
  float4* meta4  =(float4*)alloc((size_t)2*N_*16);
  float4* x4     =(float4*)alloc((size_t)2*N_*16);
  float4* rS     =(float4*)alloc((size_t)2*N_*16);
  float4* zpA4   =(float4*)alloc((size_t)2*N_*32);   // {z,p} interleaved
  float4* zpB4   =(float4*)alloc((size_t)2*N_*32);
  float4* Ap4    = splat4;        // alias: splat4 dead after k_Ar0
  float*  confr  = (float*)zpB4;  // alias: zpB first written in k_Ap it=0; confr dead after px3

  dim3 blk(256);

  // ---- init scalars (scal, count, scalD) ----
  hipMemsetAsync(wsb, 0, 4096 + 12608*8, stream);

  // ---- CNN ----
  k_maxes<<<128,blk,0,stream>>>((const float4*)image,(const float4*)feature,scal);

  // conv1: OCSPLIT=4 -> 1536 blocks (6/CU)
  k_convT<true,3,3,4,2,true,384,512,192,256,4><<<4*((B_*192*256)/256),blk,0,stream>>>(
      image,pred,w1,b1,x1,gnAcc(0),scal);
  k_gnrelu<12288><<<(B_*16*12288)/256,blk,0,stream>>>((const float4*)x1,(float4*)x1n,gnAcc(0),g1,be1);
  // conv2: OCSPLIT=8 -> 768 blocks
  k_convT<false,16,0,4,2,true,192,256,96,128,8><<<8*((B_*96*128)/256),blk,0,stream>>>(
      x1n,x1n,w2,b2,x2,gnAcc(1),scal);
  k_gnrelu<3072><<<(B_*16*3072)/256,blk,0,stream>>>((const float4*)x2,(float4*)x2n,gnAcc(1),g2,be2);
  // conv3: OCSPLIT=8 -> 768 blocks
  k_convT<false,16,0,3,1,false,96,128,96,128,8><<<8*((B_*96*128)/256),blk,0,stream>>>(
      x2n,x2n,wd1,bd1,dx1,gnAcc(2),scal);
  k_resize2x<96,128><<<(B_*16*96*128)/256,blk,0,stream>>>(dx1, dx1r, gnAcc(2), gd1, bed1);
  // conv4 (wd2): OCSPLIT=4 -> 1536 blocks (6/CU)
  k_convT<false,16,16,3,1,false,192,256,192,256,4><<<4*((B_*192*256)/256),blk,0,stream>>>(
      dx1r,x1n,wd2,bd2,dx2,gnAcc(3),scal);
  k_resize2x<192,256><<<(B_*16*192*256)/256,blk,0,stream>>>(dx2, dx2r, gnAcc(3), gd2, bed2);

  k_conv5<<<(B_*(N_/2))/256,blk,0,stream>>>(dx2r, wf, bf, confr, scal);

  // ---- bilateral solver setup ----
  hipMemsetAsync(winner, 0xFF, (size_t)2*T_*4, stream);                      // winner = -1
  hipMemsetAsync(mcomp,  0,    (size_t)2*N_*40, stream);                     // mcomp+splat4+mcompE+splatE
  k_px1<<<G2N_,blk,0,stream>>>(feature,scal,hpix,cpix2,winner);
  k_cmpA<<<G2T_,blk,0,stream>>>(winner,count,cidx2,slot_of);                 // atomic compaction
  k_px3<<<G2N_,blk,0,stream>>>(hpix,cidx2,confr,scal,confout,pred,mcomp,splat4,mcompE,splatE);

  // ---- bistochastization: fused extras-merge + nbr-build + it0, then 9 more ----
  k_bisto0<<<G2N_,blk,0,stream>>>(count,slot_of,cpix2,cidx2,nbr,mcomp,mcompE,splat4,(const float4*)splatE,nA);
  for(int it=1; it<10; ++it){
    float* src = (it&1) ? nA : nB;
    float* dst = (it&1) ? nB : nA;
    k_bisto<<<G2N_,blk,0,stream>>>(count,nbr,src,dst,mcomp);
  }
  float* nfin = nB;   // it9 (odd) wrote nB

  k_Ar0<<<G2N_,blk,0,stream>>>(count,nbr,nfin,splat4,meta4,x4,rS,zpA4,rzArr(0));

  float4* zp[2]={zpA4,zpB4};
  for(int it=0; it<12; ++it){
    float4* zpCur  = zp[it&1];
    float4* zpNext = zp[(it+1)&1];
    const double* bN = (it==0) ? zeroD : rzArr(it);
    const double* bD = (it==0) ? zeroD : rzArr(it-1);
    int bstr = (it==0) ? 0 : RZB_;
    k_Ap<<<G2N_,blk,0,stream>>>(count,nbr,meta4,zpCur,zpNext,Ap4,bN,bD,bstr,pApArr(it));
    k_upd1<<<G2N_,blk,0,stream>>>(count,x4,rS,zpNext,zpNext,Ap4,rzArr(it),pApArr(it),rzArr(it+1),(it<11)?1:0);
  }
  k_out<<<G2N_,blk,0,stream>>>(x4,hpix,outp);

  (void)in_sizes; (void)n_in; (void)out_size; (void)ws_size;
}

// Round 8
// 715.884 us; speedup vs baseline: 6.7130x; 6.7130x over previous
//
#include <hip/hip_runtime.h>

#define H_ 384
#define W_ 512
#define N_ (H_*W_)        // 196608
#define B_ 2
#define T_ 1048576
#define TMASK_ 0xFFFFFu
#define G2N_ ((2*N_)/256) // 1536
#define G2T_ ((2*T_)/256) // 8192
#define CHS_ 64           // doubles per channel accumulator block (8 subs x 8-double spacing)
// scalD layout (doubles), all accumulators 8-way sub-slot spread (64B apart):
//   [0..191]   zeroD (stays 0)
//   rz  [b][it] at 192   + b*2688 + it*192   (it=0..13)
//   pAp [b][it] at 5568  + b*2496 + it*192   (it=0..12)
//   GN acc      at 10560 + L*512 + bg*128 (+j*8 sum, +64+j*8 sumsq)
#define RZ0_ 192
#define RZB_ 2688
#define PAP0_ 5568
#define PAPB_ 2496
#define GN0_ 10560

__device__ __forceinline__ int prime(int d){
  switch(d){
    case 0: return 73856093;
    case 1: return 19349663;
    case 2: return 83492791;
    case 3: return 49979687;
    default: return 24036583;
  }
}

__device__ __forceinline__ float clampScale(float s){ return fminf(fmaxf(s,1e-5f),1.0f); }

__device__ __forceinline__ double blockReduceD(double v){
  __shared__ double sh[4];
  for(int s=32;s>0;s>>=1) v += __shfl_down(v,s,64);
  int lane=threadIdx.x&63, w=threadIdx.x>>6;
  if(lane==0) sh[w]=v;
  __syncthreads();
  double r = sh[0]+sh[1]+sh[2]+sh[3];
  __syncthreads();
  return r;
}
__device__ __forceinline__ float blockReduceMaxF(float v){
  __shared__ float sh[4];
  for(int s=32;s>0;s>>=1) v = fmaxf(v,__shfl_down(v,s,64));
  int lane=threadIdx.x&63, w=threadIdx.x>>6;
  if(lane==0) sh[w]=v;
  __syncthreads();
  float r = fmaxf(fmaxf(sh[0],sh[1]),fmaxf(sh[2],sh[3]));
  __syncthreads();
  return r;
}

// spread atomic into 8 sub-slots (separate 64B lines); consumer sums 8
__device__ __forceinline__ void redAdd(double* base, int c, double v){
  atomicAdd(&base[c*CHS_ + ((blockIdx.x&7)<<3)], v);
}
__device__ __forceinline__ float redSum(const double* base, int c){
  double s=0.0;
  #pragma unroll
  for(int j=0;j<8;j++) s += base[c*CHS_ + j*8];
  return (float)s;
}

// GN stats from the 8-way-spread double accumulator -> float mean/rstd
__device__ __forceinline__ void gnStats(const double* acc, int b, int c, double len,
                                        float* mf, float* rs){
  const double* ba = acc + (b*2 + (c>>3))*128;
  double s=0.0,s2=0.0;
  #pragma unroll
  for(int j=0;j<8;j++){ s+=ba[j*8]; s2+=ba[64+j*8]; }
  double mean = s/len;
  double var = s2/len - mean*mean;
  *rs = (float)(1.0/sqrt(var + 1e-5));
  *mf = (float)mean;
}

// ---------------- CNN kernels ----------------

__global__ __launch_bounds__(256) void k_maxes(const float4* img4, const float4* feat4, float* scal){
  const int PB = (3*N_)/4;
  for(int b=0;b<2;b++){
    float lm=0.f, lf=0.f;
    for(int idx = blockIdx.x*256+threadIdx.x; idx<PB; idx += gridDim.x*256){
      float4 a=img4[(size_t)b*PB+idx], c=feat4[(size_t)b*PB+idx];
      lm=fmaxf(lm, fmaxf(fmaxf(a.x,a.y),fmaxf(a.z,a.w)));
      lf=fmaxf(lf, fmaxf(fmaxf(c.x,c.y),fmaxf(c.z,c.w)));
    }
    lm=blockReduceMaxF(lm); lf=blockReduceMaxF(lf);
    if(threadIdx.x==0){
      atomicMax((int*)&scal[b],   __float_as_int(lm));
      atomicMax((int*)&scal[2+b], __float_as_int(lf));
    }
  }
}

// GN+relu applied elementwise once; stats once per block (blocks never span (b,c))
template<int PLANE4>
__global__ __launch_bounds__(256) void k_gnrelu(const float4* in, float4* out, const double* acc,
                                                const float* gamma, const float* beta){
  int idx = blockIdx.x*256 + threadIdx.x;   // grid exactly B*16*PLANE4/256
  int t = idx / PLANE4;
  int c = t & 15, b = t >> 4;
  __shared__ float smf, srs, sg, sbe;
  if(threadIdx.x==0){
    float mf, rs;
    gnStats(acc, b, c, 8.0*(double)(PLANE4*4), &mf, &rs);
    smf=mf; srs=rs; sg=gamma[c]; sbe=beta[c];
  }
  __syncthreads();
  float mf=smf, rs=srs, g=sg, be=sbe;
  float4 v = in[idx];
  v.x = fmaxf((v.x-mf)*rs*g+be, 0.f);
  v.y = fmaxf((v.y-mf)*rs*g+be, 0.f);
  v.z = fmaxf((v.z-mf)*rs*g+be, 0.f);
  v.w = fmaxf((v.w-mf)*rs*g+be, 0.f);
  out[idx] = v;
}

template<bool SCALEA,int NCH,int K,int S,bool EDGE,int IH,int IW,int NOC>
__device__ __forceinline__ void conv_accum(const float* __restrict__ plane0, int icBase, float sA,
                                           int oy, int ox, const float* wlds, float acc[NOC]){
  for(int ic=0; ic<NCH; ic++){
    const float* plane = plane0 + (size_t)ic*IH*IW;
    #pragma unroll
    for(int ky=0;ky<K;ky++){
      int iy = oy*S + ky - 1;
      int cy = min(max(iy,0),IH-1);
      bool yin = (iy>=0)&&(iy<IH);
      const float* row = plane + cy*IW;
      #pragma unroll
      for(int kx=0;kx<K;kx++){
        int ix = ox*S + kx - 1;
        float v;
        if(EDGE){
          int cx = min(max(ix,0),IW-1);
          v = row[cx];
          if(SCALEA) v = v / sA;
        } else {
          bool inb = yin && ix>=0 && ix<IW;
          if(inb){
            v = row[ix];
            if(SCALEA) v = v / sA;
          } else v = 0.f;
        }
        const float* wp = &wlds[((icBase+ic)*K*K + ky*K + kx)*NOC];
        #pragma unroll
        for(int q=0;q<NOC;q++) acc[q] += v*wp[q];
      }
    }
  }
}

// OCSPLIT: grid = OCSPLIT * (B*OH*OW/256); each thread computes 16/OCSPLIT output channels.
template<bool SCALEA,int ICA,int ICB,int K,int S,bool EDGE,int IH,int IW,int OH,int OW,int OCSPLIT>
__global__ __launch_bounds__(256) void k_convT(const float* __restrict__ inA, const float* __restrict__ inB,
                        const float* __restrict__ wt, const float* __restrict__ bias,
                        float* __restrict__ out, double* gnaccOut, const float* scal){
  constexpr int IC = ICA+ICB;
  constexpr int NOC = 16/OCSPLIT;
  constexpr int PB = (B_*OH*OW)/256;
  __shared__ float wlds[IC*K*K*NOC];
  __shared__ float blds[NOC];
  int pb  = blockIdx.x % PB;
  int ocg = blockIdx.x / PB;
  int ocBase = ocg*NOC;
  for(int i=threadIdx.x; i<IC*K*K*NOC; i+=256){
    int q = i % NOC, ickk = i / NOC;
    wlds[i] = wt[(ocBase+q)*IC*K*K + ickk];
  }
  if(threadIdx.x<NOC) blds[threadIdx.x]=bias[ocBase+threadIdx.x];
  __syncthreads();
  int idx = pb*256+threadIdx.x;
  int ox = idx % OW; int t=idx/OW; int oy=t%OH; int b=t/OH;   // blocks never span batches
  float sA = SCALEA ? clampScale(scal[b]) : 1.0f;
  float acc[NOC];
  #pragma unroll
  for(int q=0;q<NOC;q++) acc[q]=0.f;
  conv_accum<SCALEA,ICA,K,S,EDGE,IH,IW,NOC>(inA + (size_t)b*ICA*IH*IW, 0, sA, oy, ox, wlds, acc);
  if constexpr(ICB>0)
    conv_accum<false,(ICB>0?ICB:1),K,S,EDGE,IH,IW,NOC>(inB + (size_t)b*ICB*IH*IW, ICA, 1.0f, oy, ox, wlds, acc);
  double s=0.0,s2=0.0;
  #pragma unroll
  for(int q=0;q<NOC;q++){
    float vv = acc[q] + blds[q];
    out[(((size_t)b*16+(ocBase+q))*OH+oy)*OW+ox] = vv;
    s += vv; s2 += (double)vv*(double)vv;
  }
  s=blockReduceD(s); s2=blockReduceD(s2);
  if(threadIdx.x==0){
    int grp = ocBase>>3;                 // NOC<=8: all of a thread's channels in one GN group
    int sub = (blockIdx.x&7)<<3;
    atomicAdd(&gnaccOut[(b*2+grp)*128 + sub],      s);
    atomicAdd(&gnaccOut[(b*2+grp)*128 + 64 + sub], s2);
  }
}

// Specialized GN(+relu) + exact 2x half-pixel bilinear upsample.
template<int IH,int IW>
__global__ __launch_bounds__(256) void k_resize2x(const float* __restrict__ in, float* __restrict__ out,
                                                  const double* acc, const float* gamma, const float* beta){
  constexpr int QP = IH*IW;     // quads per plane
  constexpr int OW = 2*IW;
  int idx = blockIdx.x*256 + threadIdx.x;   // grid exactly B*16*QP/256
  int q = idx % QP; int t = idx / QP;       // t = b*16+c
  int qx = q % IW, qy = q / IW;
  int c = t & 15, b = t >> 4;
  __shared__ float smf, srs, sg, sbe;
  if(threadIdx.x==0){
    float mf, rs;
    gnStats(acc, b, c, 8.0*(double)QP, &mf, &rs);
    smf=mf; srs=rs; sg=gamma[c]; sbe=beta[c];
  }
  __syncthreads();
  float mf=smf, rs=srs, g=sg, be=sbe;
  const float* plane = in + (size_t)t*QP;
  int ym = max(qy-1,0), yp = min(qy+1,IH-1);
  int xm = max(qx-1,0), xp = min(qx+1,IW-1);
  const float* r0 = plane + ym*IW;
  const float* r1 = plane + qy*IW;
  const float* r2 = plane + yp*IW;
  float a00=fmaxf((r0[xm]-mf)*rs*g+be,0.f), a01=fmaxf((r0[qx]-mf)*rs*g+be,0.f), a02=fmaxf((r0[xp]-mf)*rs*g+be,0.f);
  float a10=fmaxf((r1[xm]-mf)*rs*g+be,0.f), a11=fmaxf((r1[qx]-mf)*rs*g+be,0.f), a12=fmaxf((r1[xp]-mf)*rs*g+be,0.f);
  float a20=fmaxf((r2[xm]-mf)*rs*g+be,0.f), a21=fmaxf((r2[qx]-mf)*rs*g+be,0.f), a22=fmaxf((r2[xp]-mf)*rs*g+be,0.f);
  float e0 = 0.25f*a00+0.75f*a01, o0 = 0.75f*a01+0.25f*a02;
  float e1 = 0.25f*a10+0.75f*a11, o1 = 0.75f*a11+0.25f*a12;
  float e2 = 0.25f*a20+0.75f*a21, o2 = 0.75f*a21+0.25f*a22;
  float2 rE = make_float2(0.25f*e0+0.75f*e1, 0.25f*o0+0.75f*o1);
  float2 rO = make_float2(0.75f*e1+0.25f*e2, 0.75f*o1+0.25f*o2);
  float* po = out + (size_t)t*(4*QP) + (size_t)(2*qy)*OW + 2*qx;
  *(float2*)po        = rE;
  *(float2*)(po + OW) = rO;
}

// conf head: TWO y-adjacent pixels per thread (shares input rows)
__global__ __launch_bounds__(256) void k_conv5(const float* in, const float* wf, const float* bf,
                                               float* confr, float* scal){
  int idx = blockIdx.x*256 + threadIdx.x;   // grid exactly B*(N/2)/256
  int ph = idx % (N_/2); int b = idx / (N_/2);
  int oyh = ph / W_, ox = ph % W_;
  int oy0 = oyh*2;
  float acc0 = bf[0], acc1 = bf[0];
  for(int ic=0; ic<16; ic++){
    const float* plane = in + ((size_t)b*16+ic)*N_;
    #pragma unroll
    for(int ky=0;ky<3;ky++){
      int iy0 = min(max(oy0+ky-1,0),H_-1);
      int iy1 = min(max(oy0+ky,0),H_-1);
      const float* row0 = plane + iy0*W_;
      const float* row1 = plane + iy1*W_;
      #pragma unroll
      for(int kx=0;kx<3;kx++){
        int ix = min(max(ox+kx-1,0),W_-1);
        float w = wf[(ic*3+ky)*3+kx];
        acc0 += row0[ix]*w;
        acc1 += row1[ix]*w;
      }
    }
  }
  float c0 = 0.5f*(tanhf(acc0)+1.0f);
  float c1 = 0.5f*(tanhf(acc1)+1.0f);
  confr[(size_t)b*N_ + oy0*W_ + ox]     = c0;
  confr[(size_t)b*N_ + (oy0+1)*W_ + ox] = c1;
  float mx = blockReduceMaxF(fmaxf(c0,c1));
  if(threadIdx.x==0) atomicMax((int*)&scal[4], __float_as_int(mx));
}

// ---------------- bilateral solver setup (both batches merged) ----------------

__global__ __launch_bounds__(256) void k_px1(const float* feat, const float* scal,
                                             int* hpix, int2* cpix2, int* winner){
  int idx = blockIdx.x*256 + threadIdx.x;   // grid exactly 2N/256
  int b = idx / N_, pix = idx % N_;
  int y = pix / W_, x = pix % W_;
  float sF = clampScale(scal[2+b]);
  const float* fb = feat + (size_t)b*3*N_;
  // exact reference eval order, no FMA contraction (coords are integer-binned)
  float R  = __fmul_rn(__fdiv_rn(fb[pix],      sF), 255.0f);
  float G  = __fmul_rn(__fdiv_rn(fb[N_+pix],   sF), 255.0f);
  float Bl = __fmul_rn(__fdiv_rn(fb[2*N_+pix], sF), 255.0f);
  float Y = __fadd_rn(__fadd_rn(__fadd_rn(__fmul_rn(0.299f,R),     __fmul_rn(0.587f,G)),  __fmul_rn(0.114f,Bl)), 0.0f);
  float U = __fadd_rn(__fadd_rn(__fadd_rn(__fmul_rn(-0.168736f,R), __fmul_rn(-0.331264f,G)), __fmul_rn(0.5f,Bl)), 128.0f);
  float V = __fadd_rn(__fadd_rn(__fadd_rn(__fmul_rn(0.5f,R),       __fmul_rn(-0.418688f,G)), __fmul_rn(-0.081312f,Bl)), 128.0f);
  int c[5];
  c[0] = (int)floorf(__fdiv_rn((float)x, 7.0f));
  c[1] = (int)floorf(__fdiv_rn((float)y, 7.0f));
  c[2] = (int)floorf(__fdiv_rn(Y, 8.0f));
  c[3] = (int)floorf(__fdiv_rn(U, 2.0f));
  c[4] = (int)floorf(__fdiv_rn(V, 2.0f));
  unsigned hh = 0;
  #pragma unroll
  for(int d=0;d<5;d++) hh += (unsigned)c[d]*(unsigned)prime(d);
  hh &= TMASK_;
  hpix[idx]=(int)hh;
  cpix2[idx]=make_int2(c[0] | (c[1]<<10) | (c[2]<<20), c[3] | (c[4]<<10));
  atomicMax(&winner[(size_t)b*T_+(int)hh], pix);   // last-writer (max pix) wins = XLA scatter
}

// --- atomic-free 3-phase compaction (r5 path; k_cmpA's 2-address atomics cost 4ms) ---

__global__ __launch_bounds__(256) void k_cnt(const int* winner, int* bcnt){
  int t = blockIdx.x*256 + threadIdx.x;   // grid exactly 2T/256
  bool occ = winner[t] >= 0;
  __shared__ int wc[4];
  unsigned long long mk = __ballot(occ);
  int lane = threadIdx.x & 63, w = threadIdx.x >> 6;
  if(lane==0) wc[w] = __popcll(mk);
  __syncthreads();
  if(threadIdx.x==0) bcnt[blockIdx.x] = wc[0]+wc[1]+wc[2]+wc[3];
}

// single-pass scan of 8192 block counts: thread t owns 32 contiguous entries
// (threads 0..127 = batch 0, 128..255 = batch 1 — 4096 boundary = thread 128).
// Produces bit-identical boff/count to the old 32-chunk serial scan, ~6x fewer barriers.
__global__ __launch_bounds__(256) void k_scan(const int* bcnt, int* boff, int* count){
  __shared__ int ssum[256];
  int t = threadIdx.x;
  int base = t*32;
  int loc[32];
  int s=0;
  #pragma unroll
  for(int j=0;j<32;j++){ loc[j]=s; s+=bcnt[base+j]; }   // local exclusive prefixes
  int mys = s;
  ssum[t]=s;
  __syncthreads();
  // inclusive Hillis-Steele within each 128-thread half (halves = batches)
  for(int st=1; st<128; st<<=1){
    int add = ((t&127) >= st) ? ssum[t-st] : 0;
    __syncthreads();
    ssum[t] += add;
    __syncthreads();
  }
  int excl = ssum[t] - mys;     // batch-local exclusive prefix for this thread's span
  #pragma unroll
  for(int j=0;j<32;j++) boff[base+j] = excl + loc[j];
  if(t==127) count[0]=ssum[127];
  if(t==255) count[1]=ssum[255];
}

__global__ __launch_bounds__(256) void k_cmp(const int* winner, const int* boff,
                                             int2* cidx2, int* slot_of){
  int t = blockIdx.x*256 + threadIdx.x;   // grid exactly 2T/256
  int b = t / T_;
  int wn = winner[t];
  bool occ = wn >= 0;
  __shared__ int wc[4];
  unsigned long long mk = __ballot(occ);
  int lane = threadIdx.x & 63, w = threadIdx.x >> 6;
  if(lane==0) wc[w] = __popcll(mk);
  __syncthreads();
  int wpre = 0;
  for(int k2=0;k2<4;k2++) if(k2<w) wpre += wc[k2];
  if(occ){
    int li = boff[blockIdx.x] + wpre + __popcll(mk & ((1ull<<lane)-1ull));
    int gi = b*N_ + li;
    cidx2[t] = make_int2(gi, wn);
    slot_of[gi] = t - b*T_;    // local slot hh
  }
}

// conf normalize + splat: winner plain-stores; non-winners (~10%) atomicAdd into extras
__global__ __launch_bounds__(256) void k_px3(int* hpix_gpix, const int2* cidx2, const float* confr,
                                             const float* scal, float* confout, const float* pred,
                                             float* mcomp, float4* splat4, float* mcompE, float* splatE){
  int idx = blockIdx.x*256 + threadIdx.x;   // grid exactly 2N/256
  int b = idx / N_, pix = idx % N_;
  int2 cw = cidx2[(size_t)b*T_ + hpix_gpix[idx]];
  int gi = cw.x;
  hpix_gpix[idx] = gi;
  float w = confr[idx] / fmaxf(scal[4], 1e-5f);
  confout[idx] = w;
  const float* pb = pred + (size_t)b*3*N_;
  float v0 = __fmul_rn(w, pb[pix]);
  float v1 = __fmul_rn(w, pb[N_+pix]);
  float v2 = __fmul_rn(w, pb[2*N_+pix]);
  if(cw.y == pix){
    splat4[gi] = make_float4(v0,v1,v2,w);
    mcomp[gi] = 1.0f;
  } else {
    float* s = splatE + 4*(size_t)gi;
    atomicAdd(s+0, v0);
    atomicAdd(s+1, v1);
    atomicAdd(s+2, v2);
    atomicAdd(s+3, w);
    atomicAdd(&mcompE[gi], 1.0f);
  }
}

// ---------------- solver kernels (proven r5 CG path) ----------------
// CG state packing: zp[2i] = {z0,z1,z2,mi}, zp[2i+1] = {p0,p1,p2,nv} — one 64B line
// per neighbor gather in k_Ap.

// fused: merge extras + neighbor-table build + first bisto iter (n0=1)
__global__ __launch_bounds__(256) void k_bisto0(const int* count, const int* slot_of,
                      const int2* cpix2, const int2* cidx2, int* nbr,
                      float* mcomp, const float* mcompE, float4* splat4, const float4* splatE4,
                      float* nd){
  int i = blockIdx.x*256 + threadIdx.x;     // grid exactly 2N/256
  int b = i / N_, li = i - b*N_;
  if(li >= count[b]) return;
  int hh = slot_of[i];
  const int2* c2b = cidx2 + (size_t)b*T_;
  int2 cself = c2b[hh];
  int2 cp = cpix2[(size_t)b*N_ + cself.y];
  float4 sp = splat4[i]; float4 se = splatE4[i];
  sp.x+=se.x; sp.y+=se.y; sp.z+=se.z; sp.w+=se.w;
  splat4[i]=sp;
  float mTot = mcomp[i] + mcompE[i];
  mcomp[i]=mTot;
  float bv = 10.f;
  #pragma unroll
  for(int j=0;j<10;j++){
    int d=j>>1; int off=(j&1)?1:-1;
    unsigned nh = ((unsigned)hh + (unsigned)(off*prime(d))) & TMASK_;
    int nb = -1;
    int2 cn2 = c2b[nh];
    if(cn2.y>=0){
      int2 cn = cpix2[(size_t)b*N_ + cn2.y];
      int e0 = cp.x + (d==0?off: d==1?off*(1<<10) : d==2?off*(1<<20) : 0);
      int e1 = cp.y + (d==3?off: d==4?off*(1<<10) : 0);
      if(cn.x==e0 && cn.y==e1) nb = cn2.x;
    }
    nbr[(size_t)j*(2*N_)+i]=nb;
    if(nb>=0) bv += 1.0f;
  }
  nd[i] = sqrtf(1.0f*mTot/(bv+1e-12f));
}

__global__ __launch_bounds__(256) void k_bisto(const int* count, const int* nbr,
                                               const float* ns, float* nd, const float* mc){
  int i = blockIdx.x*256 + threadIdx.x;
  int b = i / N_, li = i - b*N_;
  if(li >= count[b]) return;
  float nv = ns[i];
  float bv = 10.f*nv;
  #pragma unroll
  for(int j=0;j<10;j++){
    int nb = nbr[(size_t)j*(2*N_)+i];
    if(nb>=0) bv += ns[nb];
  }
  nd[i] = sqrtf(nv*mc[i]/(bv+1e-12f));
}

// fused mfinal + x0 + A(x0) + r0/z0/p0 + rz0 per-batch reduction
__global__ __launch_bounds__(256) void k_Ar0(const int* count, const int* nbr, const float* n,
                      const float4* splat4, float4* meta4, float4* x4, float4* rS, float4* zp0,
                      double* rz0){
  int i = blockIdx.x*256 + threadIdx.x;
  int b = i / N_, li = i - b*N_;
  double a0=0.0,a1=0.0,a2=0.0;
  if(li < count[b]){
    float4 vb4 = splat4[i];
    float wsi = vb4.w;
    float nv = n[i];
    float x0 = vb4.x/(wsi+1e-12f);
    float x1 = vb4.y/(wsi+1e-12f);
    float x2 = vb4.z/(wsi+1e-12f);
    float bv = 10.f*nv;
    float s0=10.f*(nv*x0), s1=10.f*(nv*x1), s2=10.f*(nv*x2);
    #pragma unroll
    for(int j=0;j<10;j++){
      int nb = nbr[(size_t)j*(2*N_)+i];
      if(nb>=0){
        float4 vbn = splat4[nb];
        float nn = n[nb];
        bv += nn;
        s0 += nn*(vbn.x/(vbn.w+1e-12f));
        s1 += nn*(vbn.y/(vbn.w+1e-12f));
        s2 += nn*(vbn.z/(vbn.w+1e-12f));
      }
    }
    float mfin = nv*bv;
    float Ad = fmaxf(200.0f*(mfin - 10.f*nv*nv) + wsi, 1e-5f);
    float mi = 1.0f/Ad;
    float A0 = 200.f*(mfin*x0 - nv*s0) + wsi*x0;
    float A1 = 200.f*(mfin*x1 - nv*s1) + wsi*x1;
    float A2 = 200.f*(mfin*x2 - nv*s2) + wsi*x2;
    float r0v = vb4.x-A0, r1v = vb4.y-A1, r2v = vb4.z-A2;
    float z0=mi*r0v, z1=mi*r1v, z2=mi*r2v;
    meta4[i]=make_float4(nv,mfin,wsi,mi);
    x4[i]=make_float4(x0,x1,x2,0.f);
    rS[i]=make_float4(r0v,r1v,r2v,mi);
    zp0[2*(size_t)i]   = make_float4(z0,z1,z2,mi);
    zp0[2*(size_t)i+1] = make_float4(z0,z1,z2,nv);   // p0 = z0
    a0=(double)r0v*z0; a1=(double)r1v*z1; a2=(double)r2v*z2;
  }
  a0=blockReduceD(a0); a1=blockReduceD(a1); a2=blockReduceD(a2);
  if(threadIdx.x==0){
    double* base = rz0 + b*RZB_;
    redAdd(base,0,a0); redAdd(base,1,a1); redAdd(base,2,a2);
  }
}

// fused p-update + A: p = z + beta*pOld; gathers one 64B {z,p} line per neighbor.
// beta computed once per block (thread 0).
__global__ __launch_bounds__(256) void k_Ap(const int* count, const int* nbr, const float4* meta4,
                     const float4* __restrict__ zpCur, float4* __restrict__ zpNext, float4* Ap4,
                     const double* bNum, const double* bDen, int bstr, double* pAp){
  int i = blockIdx.x*256 + threadIdx.x;
  int b = (blockIdx.x*256) / N_;      // blocks never span batches
  int li = i - b*N_;
  __shared__ float sbe[3];
  if(threadIdx.x==0){
    if(bstr==0){ sbe[0]=0.f; sbe[1]=0.f; sbe[2]=0.f; }
    else{
      const double* nB_ = bNum + b*bstr;
      const double* dB_ = bDen + b*bstr;
      #pragma unroll
      for(int c=0;c<3;c++) sbe[c] = redSum(nB_,c) / (redSum(dB_,c)+1e-12f);
    }
  }
  __syncthreads();
  float be0=sbe[0], be1=sbe[1], be2=sbe[2];
  double a0=0.0,a1=0.0,a2=0.0;
  if(li < count[b]){
    float4 mt = meta4[i];
    float nv = mt.x, mfin = mt.y, wsi = mt.z;
    float4 zs = zpCur[2*(size_t)i];
    float4 ps = zpCur[2*(size_t)i+1];
    float p0 = zs.x + be0*ps.x;
    float p1 = zs.y + be1*ps.y;
    float p2 = zs.z + be2*ps.z;
    float s0=10.f*(nv*p0), s1=10.f*(nv*p1), s2=10.f*(nv*p2);
    #pragma unroll
    for(int j=0;j<10;j++){
      int nb = nbr[(size_t)j*(2*N_)+i];
      if(nb>=0){
        float4 zn = zpCur[2*(size_t)nb];
        float4 pn = zpCur[2*(size_t)nb+1];
        float nn = pn.w;
        s0 += nn*(zn.x + be0*pn.x);
        s1 += nn*(zn.y + be1*pn.y);
        s2 += nn*(zn.z + be2*pn.z);
      }
    }
    float A0 = 200.f*(mfin*p0 - nv*s0) + wsi*p0;
    float A1 = 200.f*(mfin*p1 - nv*s1) + wsi*p1;
    float A2 = 200.f*(mfin*p2 - nv*s2) + wsi*p2;
    zpNext[2*(size_t)i+1]=make_float4(p0,p1,p2,nv);
    Ap4[i]=make_float4(A0,A1,A2,0.f);
    a0=(double)p0*A0; a1=(double)p1*A1; a2=(double)p2*A2;
  }
  a0=blockReduceD(a0); a1=blockReduceD(a1); a2=blockReduceD(a2);
  if(threadIdx.x==0){
    double* base = pAp + b*PAPB_;
    redAdd(base,0,a0); redAdd(base,1,a1); redAdd(base,2,a2);
  }
}

// x/r update + z for next iter; alpha computed once per block (thread 0)
__global__ __launch_bounds__(256) void k_upd1(const int* count, float4* x4, float4* rS,
                       const float4* __restrict__ zpNext_p, float4* __restrict__ zpNext_z,
                       const float4* Ap4,
                       const double* rzCur, const double* pApC, double* rzNew, int doRz){
  int i = blockIdx.x*256 + threadIdx.x;
  int b = (blockIdx.x*256) / N_;
  int li = i - b*N_;
  __shared__ float sal[3];
  if(threadIdx.x==0){
    const double* rc = rzCur + b*RZB_;
    const double* pc = pApC  + b*PAPB_;
    #pragma unroll
    for(int c=0;c<3;c++) sal[c] = redSum(rc,c) / (redSum(pc,c)+1e-12f);
  }
  __syncthreads();
  float al0=sal[0], al1=sal[1], al2=sal[2];
  double a0=0.0,a1=0.0,a2=0.0;
  if(li < count[b]){
    float4 xv = x4[i];
    float4 rv = rS[i];
    float4 pv = zpNext_p[2*(size_t)i+1];
    float4 av = Ap4[i];
    float mi = rv.w;
    float x0=xv.x+al0*pv.x, x1=xv.y+al1*pv.y, x2=xv.z+al2*pv.z;
    float r0v=rv.x-al0*av.x, r1v=rv.y-al1*av.y, r2v=rv.z-al2*av.z;
    float z0=mi*r0v, z1=mi*r1v, z2=mi*r2v;
    x4[i]=make_float4(x0,x1,x2,0.f);
    rS[i]=make_float4(r0v,r1v,r2v,mi);
    zpNext_z[2*(size_t)i]=make_float4(z0,z1,z2,mi);
    a0=(double)r0v*z0; a1=(double)r1v*z1; a2=(double)r2v*z2;
  }
  if(doRz){
    a0=blockReduceD(a0); a1=blockReduceD(a1); a2=blockReduceD(a2);
    if(threadIdx.x==0){
      double* base = rzNew + b*RZB_;
      redAdd(base,0,a0); redAdd(base,1,a1); redAdd(base,2,a2);
    }
  }
}

__global__ __launch_bounds__(256) void k_out(const float4* x4, const int* gpix, float* out){
  int idx = blockIdx.x*256 + threadIdx.x;   // grid exactly 2N/256
  int b = idx / N_, pix = idx % N_;
  float4 xv = x4[gpix[idx]];
  out[((size_t)(b*3+0))*N_+pix] = xv.x;
  out[((size_t)(b*3+1))*N_+pix] = xv.y;
  out[((size_t)(b*3+2))*N_+pix] = xv.z;
}

// ---------------- host launcher ----------------

extern "C" void kernel_launch(void* const* d_in, const int* in_sizes, int n_in,
                              void* d_out, int out_size, void* d_ws, size_t ws_size,
                              hipStream_t stream){
  const float* image=(const float*)d_in[0];
  const float* feature=(const float*)d_in[1];
  const float* pred=(const float*)d_in[2];
  const float* w1=(const float*)d_in[3];  const float* b1=(const float*)d_in[4];
  const float* g1=(const float*)d_in[5];  const float* be1=(const float*)d_in[6];
  const float* w2=(const float*)d_in[7];  const float* b2=(const float*)d_in[8];
  const float* g2=(const float*)d_in[9];  const float* be2=(const float*)d_in[10];
  const float* wd1=(const float*)d_in[11];const float* bd1=(const float*)d_in[12];
  const float* gd1=(const float*)d_in[13];const float* bed1=(const float*)d_in[14];
  const float* wd2=(const float*)d_in[15];const float* bd2=(const float*)d_in[16];
  const float* gd2=(const float*)d_in[17];const float* bed2=(const float*)d_in[18];
  const float* wf=(const float*)d_in[19]; const float* bf=(const float*)d_in[20];
  float* outp=(float*)d_out;                          // (B,3,H,W)
  float* confout = outp + (size_t)B_*3*N_;            // (B,1,H,W)

  char* wsb=(char*)d_ws;
  float* scal=(float*)wsb;                  // [0..1] imgmax, [2..3] featmax, [4] confmax
  int* count=(int*)(wsb+256);               // count[2]
  double* scalD=(double*)(wsb+4096);        // 12608 doubles (see layout defines)
  double* zeroD = scalD;
  auto rzArr  = [&](int it)->double*{ return scalD + RZ0_  + it*192; };   // batch stride RZB_
  auto pApArr = [&](int it)->double*{ return scalD + PAP0_ + it*192; };   // batch stride PAPB_
  auto gnAcc  = [&](int L)->double*{ return scalD + GN0_ + L*512; };

  size_t off = 131072;
  auto alloc=[&](size_t bytes)->char*{ char* pp=wsb+off; off=(off+bytes+255)&~(size_t)255; return pp; };
  const size_t ALLOC0 = off;

  // CNN region (dead once conf is in confr; bilateral region overlaps it)
  float* x1   =(float*)alloc((size_t)B_*16*192*256*4);
  float* x1n  =(float*)alloc((size_t)B_*16*192*256*4);
  float* x2   =(float*)alloc((size_t)B_*16*96*128*4);
  float* x2n  =(float*)alloc((size_t)B_*16*96*128*4);
  float* dx1  =(float*)alloc((size_t)B_*16*96*128*4);
  float* dx1r =(float*)alloc((size_t)B_*16*192*256*4);
  float* dx2  =(float*)alloc((size_t)B_*16*192*256*4);
  float* dx2r =(float*)alloc((size_t)B_*16*N_*4);

  // bilateral region (reset offset: CNN buffers dead before the solver memsets/writes)
  off = ALLOC0;
  int*    winner =(int*)   alloc((size_t)2*T_*4);
  int2*   cidx2  =(int2*)  alloc((size_t)2*T_*8);
  int*    hpix   =(int*)   alloc((size_t)2*N_*4);    // becomes gpix after k_px3
  int2*   cpix2  =(int2*)  alloc((size_t)2*N_*8);
  int*    slot_of=(int*)   alloc((size_t)2*N_*4);
  int*    nbr    =(int*)   alloc((size_t)2*N_*10*4);
  float*  mcomp  =(float*) alloc((size_t)2*N_*4);    // mcomp..splatE contiguous: one memset
  float4* splat4 =(float4*)alloc((size_t)2*N_*16);
  float*  mcompE =(float*) alloc((size_t)2*N_*4);
  float*  splatE =(float*) alloc((size_t)2*N_*16);
  float*  nA     =(float*) alloc((size_t)2*N_*4);
  float*  nB     =(float*) alloc((size_t)2*N_*4);
  float4* meta4  =(float4*)alloc((size_t)2*N_*16);
  float4* x4     =(float4*)alloc((size_t)2*N_*16);
  float4* rS     =(float4*)alloc((size_t)2*N_*16);
  float4* zpA4   =(float4*)alloc((size_t)2*N_*32);   // {z,p} interleaved
  float4* zpB4   =(float4*)alloc((size_t)2*N_*32);
  int*    bcnt   =(int*)   alloc((size_t)G2T_*4);
  int*    boff   =(int*)   alloc((size_t)G2T_*4);
  float4* Ap4    = splat4;        // alias: splat4 dead after k_Ar0
  float*  confr  = (float*)zpB4;  // alias: zpB first written in k_Ap it=0; confr dead after px3

  dim3 blk(256);

  // ---- init scalars (scal, count, scalD) ----
  hipMemsetAsync(wsb, 0, 4096 + 12608*8, stream);

  // ---- CNN ----
  k_maxes<<<128,blk,0,stream>>>((const float4*)image,(const float4*)feature,scal);

  // conv1: OCSPLIT=4 -> 1536 blocks (6/CU)
  k_convT<true,3,3,4,2,true,384,512,192,256,4><<<4*((B_*192*256)/256),blk,0,stream>>>(
      image,pred,w1,b1,x1,gnAcc(0),scal);
  k_gnrelu<12288><<<(B_*16*12288)/256,blk,0,stream>>>((const float4*)x1,(float4*)x1n,gnAcc(0),g1,be1);
  // conv2: OCSPLIT=8 -> 768 blocks
  k_convT<false,16,0,4,2,true,192,256,96,128,8><<<8*((B_*96*128)/256),blk,0,stream>>>(
      x1n,x1n,w2,b2,x2,gnAcc(1),scal);
  k_gnrelu<3072><<<(B_*16*3072)/256,blk,0,stream>>>((const float4*)x2,(float4*)x2n,gnAcc(1),g2,be2);
  // conv3: OCSPLIT=8 -> 768 blocks
  k_convT<false,16,0,3,1,false,96,128,96,128,8><<<8*((B_*96*128)/256),blk,0,stream>>>(
      x2n,x2n,wd1,bd1,dx1,gnAcc(2),scal);
  k_resize2x<96,128><<<(B_*16*96*128)/256,blk,0,stream>>>(dx1, dx1r, gnAcc(2), gd1, bed1);
  // conv4 (wd2): OCSPLIT=4 -> 1536 blocks (6/CU)
  k_convT<false,16,16,3,1,false,192,256,192,256,4><<<4*((B_*192*256)/256),blk,0,stream>>>(
      dx1r,x1n,wd2,bd2,dx2,gnAcc(3),scal);
  k_resize2x<192,256><<<(B_*16*192*256)/256,blk,0,stream>>>(dx2, dx2r, gnAcc(3), gd2, bed2);

  k_conv5<<<(B_*(N_/2))/256,blk,0,stream>>>(dx2r, wf, bf, confr, scal);

  // ---- bilateral solver setup ----
  hipMemsetAsync(winner, 0xFF, (size_t)2*T_*4, stream);                      // winner = -1
  hipMemsetAsync(cidx2,  0xFF, (size_t)2*T_*8, stream);                      // .y=-1 = unoccupied
  hipMemsetAsync(mcomp,  0,    (size_t)2*N_*40, stream);                     // mcomp+splat4+mcompE+splatE
  k_px1<<<G2N_,blk,0,stream>>>(feature,scal,hpix,cpix2,winner);
  k_cnt<<<G2T_,blk,0,stream>>>(winner,bcnt);
  k_scan<<<1,blk,0,stream>>>(bcnt,boff,count);
  k_cmp<<<G2T_,blk,0,stream>>>(winner,boff,cidx2,slot_of);
  k_px3<<<G2N_,blk,0,stream>>>(hpix,cidx2,confr,scal,confout,pred,mcomp,splat4,mcompE,splatE);

  // ---- bistochastization: fused extras-merge + nbr-build + it0, then 9 more ----
  k_bisto0<<<G2N_,blk,0,stream>>>(count,slot_of,cpix2,cidx2,nbr,mcomp,mcompE,splat4,(const float4*)splatE,nA);
  for(int it=1; it<10; ++it){
    float* src = (it&1) ? nA : nB;
    float* dst = (it&1) ? nB : nA;
    k_bisto<<<G2N_,blk,0,stream>>>(count,nbr,src,dst,mcomp);
  }
  float* nfin = nB;   // it9 (odd) wrote nB

  k_Ar0<<<G2N_,blk,0,stream>>>(count,nbr,nfin,splat4,meta4,x4,rS,zpA4,rzArr(0));

  float4* zp[2]={zpA4,zpB4};
  for(int it=0; it<12; ++it){
    float4* zpCur  = zp[it&1];
    float4* zpNext = zp[(it+1)&1];
    const double* bN = (it==0) ? zeroD : rzArr(it);
    const double* bD = (it==0) ? zeroD : rzArr(it-1);
    int bstr = (it==0) ? 0 : RZB_;
    k_Ap<<<G2N_,blk,0,stream>>>(count,nbr,meta4,zpCur,zpNext,Ap4,bN,bD,bstr,pApArr(it));
    k_upd1<<<G2N_,blk,0,stream>>>(count,x4,rS,zpNext,zpNext,Ap4,rzArr(it),pApArr(it),rzArr(it+1),(it<11)?1:0);
  }
  k_out<<<G2N_,blk,0,stream>>>(x4,hpix,outp);

  (void)in_sizes; (void)n_in; (void)out_size; (void)ws_size;
}

// Round 9
// 699.112 us; speedup vs baseline: 6.8740x; 1.0240x over previous
//
#include <hip/hip_runtime.h>

#define H_ 384
#define W_ 512
#define N_ (H_*W_)        // 196608
#define B_ 2
#define T_ 1048576
#define TMASK_ 0xFFFFFu
#define G2N_ ((2*N_)/256) // 1536
#define G2T_ ((2*T_)/256) // 8192
#define CHS_ 64           // doubles per channel accumulator block (8 subs x 8-double spacing)
// scalD layout (doubles), all accumulators 8-way sub-slot spread (64B apart):
//   [0..191]   zeroD (stays 0)
//   rz  [b][it] at 192   + b*2688 + it*192   (it=0..13)
//   pAp [b][it] at 5568  + b*2496 + it*192   (it=0..12)
//   GN acc      at 10560 + L*512 + bg*128 (+j*8 sum, +64+j*8 sumsq)
#define RZ0_ 192
#define RZB_ 2688
#define PAP0_ 5568
#define PAPB_ 2496
#define GN0_ 10560

__device__ __forceinline__ int prime(int d){
  switch(d){
    case 0: return 73856093;
    case 1: return 19349663;
    case 2: return 83492791;
    case 3: return 49979687;
    default: return 24036583;
  }
}

__device__ __forceinline__ float clampScale(float s){ return fminf(fmaxf(s,1e-5f),1.0f); }

__device__ __forceinline__ double blockReduceD(double v){
  __shared__ double sh[4];
  for(int s=32;s>0;s>>=1) v += __shfl_down(v,s,64);
  int lane=threadIdx.x&63, w=threadIdx.x>>6;
  if(lane==0) sh[w]=v;
  __syncthreads();
  double r = sh[0]+sh[1]+sh[2]+sh[3];
  __syncthreads();
  return r;
}
__device__ __forceinline__ float blockReduceMaxF(float v){
  __shared__ float sh[4];
  for(int s=32;s>0;s>>=1) v = fmaxf(v,__shfl_down(v,s,64));
  int lane=threadIdx.x&63, w=threadIdx.x>>6;
  if(lane==0) sh[w]=v;
  __syncthreads();
  float r = fmaxf(fmaxf(sh[0],sh[1]),fmaxf(sh[2],sh[3]));
  __syncthreads();
  return r;
}

// spread atomic into 8 sub-slots (separate 64B lines); consumer sums 8
__device__ __forceinline__ void redAdd(double* base, int c, double v){
  atomicAdd(&base[c*CHS_ + ((blockIdx.x&7)<<3)], v);
}
__device__ __forceinline__ float redSum(const double* base, int c){
  double s=0.0;
  #pragma unroll
  for(int j=0;j<8;j++) s += base[c*CHS_ + j*8];
  return (float)s;
}

// GN stats from the 8-way-spread double accumulator -> float mean/rstd
__device__ __forceinline__ void gnStats(const double* acc, int b, int c, double len,
                                        float* mf, float* rs){
  const double* ba = acc + (b*2 + (c>>3))*128;
  double s=0.0,s2=0.0;
  #pragma unroll
  for(int j=0;j<8;j++){ s+=ba[j*8]; s2+=ba[64+j*8]; }
  double mean = s/len;
  double var = s2/len - mean*mean;
  *rs = (float)(1.0/sqrt(var + 1e-5));
  *mf = (float)mean;
}

// ---------------- CNN kernels ----------------

__global__ __launch_bounds__(256) void k_maxes(const float4* img4, const float4* feat4, float* scal){
  const int PB = (3*N_)/4;
  for(int b=0;b<2;b++){
    float lm=0.f, lf=0.f;
    for(int idx = blockIdx.x*256+threadIdx.x; idx<PB; idx += gridDim.x*256){
      float4 a=img4[(size_t)b*PB+idx], c=feat4[(size_t)b*PB+idx];
      lm=fmaxf(lm, fmaxf(fmaxf(a.x,a.y),fmaxf(a.z,a.w)));
      lf=fmaxf(lf, fmaxf(fmaxf(c.x,c.y),fmaxf(c.z,c.w)));
    }
    lm=blockReduceMaxF(lm); lf=blockReduceMaxF(lf);
    if(threadIdx.x==0){
      atomicMax((int*)&scal[b],   __float_as_int(lm));
      atomicMax((int*)&scal[2+b], __float_as_int(lf));
    }
  }
}

// GN+relu applied elementwise once; stats once per block (blocks never span (b,c))
template<int PLANE4>
__global__ __launch_bounds__(256) void k_gnrelu(const float4* in, float4* out, const double* acc,
                                                const float* gamma, const float* beta){
  int idx = blockIdx.x*256 + threadIdx.x;   // grid exactly B*16*PLANE4/256
  int t = idx / PLANE4;
  int c = t & 15, b = t >> 4;
  __shared__ float smf, srs, sg, sbe;
  if(threadIdx.x==0){
    float mf, rs;
    gnStats(acc, b, c, 8.0*(double)(PLANE4*4), &mf, &rs);
    smf=mf; srs=rs; sg=gamma[c]; sbe=beta[c];
  }
  __syncthreads();
  float mf=smf, rs=srs, g=sg, be=sbe;
  float4 v = in[idx];
  v.x = fmaxf((v.x-mf)*rs*g+be, 0.f);
  v.y = fmaxf((v.y-mf)*rs*g+be, 0.f);
  v.z = fmaxf((v.z-mf)*rs*g+be, 0.f);
  v.w = fmaxf((v.w-mf)*rs*g+be, 0.f);
  out[idx] = v;
}

// mulA: per-tap scale as a MULTIPLY (reciprocal hoisted by caller) — the per-tap
// v/sA divide was ~96 v_div sequences (~8 VALU each) per thread in conv1.
template<bool SCALEA,int NCH,int K,int S,bool EDGE,int IH,int IW,int NOC>
__device__ __forceinline__ void conv_accum(const float* __restrict__ plane0, int icBase, float mulA,
                                           int oy, int ox, const float* wlds, float acc[NOC]){
  for(int ic=0; ic<NCH; ic++){
    const float* plane = plane0 + (size_t)ic*IH*IW;
    #pragma unroll
    for(int ky=0;ky<K;ky++){
      int iy = oy*S + ky - 1;
      int cy = min(max(iy,0),IH-1);
      bool yin = (iy>=0)&&(iy<IH);
      const float* row = plane + cy*IW;
      #pragma unroll
      for(int kx=0;kx<K;kx++){
        int ix = ox*S + kx - 1;
        float v;
        if(EDGE){
          int cx = min(max(ix,0),IW-1);
          v = row[cx];
          if(SCALEA) v = v * mulA;
        } else {
          bool inb = yin && ix>=0 && ix<IW;
          if(inb){
            v = row[ix];
            if(SCALEA) v = v * mulA;
          } else v = 0.f;
        }
        const float* wp = &wlds[((icBase+ic)*K*K + ky*K + kx)*NOC];
        #pragma unroll
        for(int q=0;q<NOC;q++) acc[q] += v*wp[q];
      }
    }
  }
}

// OCSPLIT: grid = OCSPLIT * (B*OH*OW/256); each thread computes 16/OCSPLIT output channels.
template<bool SCALEA,int ICA,int ICB,int K,int S,bool EDGE,int IH,int IW,int OH,int OW,int OCSPLIT>
__global__ __launch_bounds__(256) void k_convT(const float* __restrict__ inA, const float* __restrict__ inB,
                        const float* __restrict__ wt, const float* __restrict__ bias,
                        float* __restrict__ out, double* gnaccOut, const float* scal){
  constexpr int IC = ICA+ICB;
  constexpr int NOC = 16/OCSPLIT;
  constexpr int PB = (B_*OH*OW)/256;
  __shared__ float wlds[IC*K*K*NOC];
  __shared__ float blds[NOC];
  int pb  = blockIdx.x % PB;
  int ocg = blockIdx.x / PB;
  int ocBase = ocg*NOC;
  for(int i=threadIdx.x; i<IC*K*K*NOC; i+=256){
    int q = i % NOC, ickk = i / NOC;
    wlds[i] = wt[(ocBase+q)*IC*K*K + ickk];
  }
  if(threadIdx.x<NOC) blds[threadIdx.x]=bias[ocBase+threadIdx.x];
  __syncthreads();
  int idx = pb*256+threadIdx.x;
  int ox = idx % OW; int t=idx/OW; int oy=t%OH; int b=t/OH;   // blocks never span batches
  float mulA = SCALEA ? 1.0f/clampScale(scal[b]) : 1.0f;      // one divide, uniform
  float acc[NOC];
  #pragma unroll
  for(int q=0;q<NOC;q++) acc[q]=0.f;
  conv_accum<SCALEA,ICA,K,S,EDGE,IH,IW,NOC>(inA + (size_t)b*ICA*IH*IW, 0, mulA, oy, ox, wlds, acc);
  if constexpr(ICB>0)
    conv_accum<false,(ICB>0?ICB:1),K,S,EDGE,IH,IW,NOC>(inB + (size_t)b*ICB*IH*IW, ICA, 1.0f, oy, ox, wlds, acc);
  double s=0.0,s2=0.0;
  #pragma unroll
  for(int q=0;q<NOC;q++){
    float vv = acc[q] + blds[q];
    out[(((size_t)b*16+(ocBase+q))*OH+oy)*OW+ox] = vv;
    s += vv; s2 += (double)vv*(double)vv;
  }
  s=blockReduceD(s); s2=blockReduceD(s2);
  if(threadIdx.x==0){
    int grp = ocBase>>3;                 // NOC<=8: all of a thread's channels in one GN group
    int sub = (blockIdx.x&7)<<3;
    atomicAdd(&gnaccOut[(b*2+grp)*128 + sub],      s);
    atomicAdd(&gnaccOut[(b*2+grp)*128 + 64 + sub], s2);
  }
}

// Specialized GN(+relu) + exact 2x half-pixel bilinear upsample.
template<int IH,int IW>
__global__ __launch_bounds__(256) void k_resize2x(const float* __restrict__ in, float* __restrict__ out,
                                                  const double* acc, const float* gamma, const float* beta){
  constexpr int QP = IH*IW;     // quads per plane
  constexpr int OW = 2*IW;
  int idx = blockIdx.x*256 + threadIdx.x;   // grid exactly B*16*QP/256
  int q = idx % QP; int t = idx / QP;       // t = b*16+c
  int qx = q % IW, qy = q / IW;
  int c = t & 15, b = t >> 4;
  __shared__ float smf, srs, sg, sbe;
  if(threadIdx.x==0){
    float mf, rs;
    gnStats(acc, b, c, 8.0*(double)QP, &mf, &rs);
    smf=mf; srs=rs; sg=gamma[c]; sbe=beta[c];
  }
  __syncthreads();
  float mf=smf, rs=srs, g=sg, be=sbe;
  const float* plane = in + (size_t)t*QP;
  int ym = max(qy-1,0), yp = min(qy+1,IH-1);
  int xm = max(qx-1,0), xp = min(qx+1,IW-1);
  const float* r0 = plane + ym*IW;
  const float* r1 = plane + qy*IW;
  const float* r2 = plane + yp*IW;
  float a00=fmaxf((r0[xm]-mf)*rs*g+be,0.f), a01=fmaxf((r0[qx]-mf)*rs*g+be,0.f), a02=fmaxf((r0[xp]-mf)*rs*g+be,0.f);
  float a10=fmaxf((r1[xm]-mf)*rs*g+be,0.f), a11=fmaxf((r1[qx]-mf)*rs*g+be,0.f), a12=fmaxf((r1[xp]-mf)*rs*g+be,0.f);
  float a20=fmaxf((r2[xm]-mf)*rs*g+be,0.f), a21=fmaxf((r2[qx]-mf)*rs*g+be,0.f), a22=fmaxf((r2[xp]-mf)*rs*g+be,0.f);
  float e0 = 0.25f*a00+0.75f*a01, o0 = 0.75f*a01+0.25f*a02;
  float e1 = 0.25f*a10+0.75f*a11, o1 = 0.75f*a11+0.25f*a12;
  float e2 = 0.25f*a20+0.75f*a21, o2 = 0.75f*a21+0.25f*a22;
  float2 rE = make_float2(0.25f*e0+0.75f*e1, 0.25f*o0+0.75f*o1);
  float2 rO = make_float2(0.75f*e1+0.25f*e2, 0.75f*o1+0.25f*o2);
  float* po = out + (size_t)t*(4*QP) + (size_t)(2*qy)*OW + 2*qx;
  *(float2*)po        = rE;
  *(float2*)(po + OW) = rO;
}

// conf head: TWO y-adjacent pixels per thread (shares input rows)
__global__ __launch_bounds__(256) void k_conv5(const float* in, const float* wf, const float* bf,
                                               float* confr, float* scal){
  int idx = blockIdx.x*256 + threadIdx.x;   // grid exactly B*(N/2)/256
  int ph = idx % (N_/2); int b = idx / (N_/2);
  int oyh = ph / W_, ox = ph % W_;
  int oy0 = oyh*2;
  float acc0 = bf[0], acc1 = bf[0];
  for(int ic=0; ic<16; ic++){
    const float* plane = in + ((size_t)b*16+ic)*N_;
    #pragma unroll
    for(int ky=0;ky<3;ky++){
      int iy0 = min(max(oy0+ky-1,0),H_-1);
      int iy1 = min(max(oy0+ky,0),H_-1);
      const float* row0 = plane + iy0*W_;
      const float* row1 = plane + iy1*W_;
      #pragma unroll
      for(int kx=0;kx<3;kx++){
        int ix = min(max(ox+kx-1,0),W_-1);
        float w = wf[(ic*3+ky)*3+kx];
        acc0 += row0[ix]*w;
        acc1 += row1[ix]*w;
      }
    }
  }
  float c0 = 0.5f*(tanhf(acc0)+1.0f);
  float c1 = 0.5f*(tanhf(acc1)+1.0f);
  confr[(size_t)b*N_ + oy0*W_ + ox]     = c0;
  confr[(size_t)b*N_ + (oy0+1)*W_ + ox] = c1;
  float mx = blockReduceMaxF(fmaxf(c0,c1));
  if(threadIdx.x==0) atomicMax((int*)&scal[4], __float_as_int(mx));
}

// ---------------- bilateral solver setup (both batches merged) ----------------

// also zeroes the atomic-extras arrays (mcompE/splatE), replacing a 15.7MB memset;
// mcomp/splat4 need no init: px3's winner branch overwrites every occupied cell
// and unoccupied cells are never read downstream.
__global__ __launch_bounds__(256) void k_px1(const float* feat, const float* scal,
                                             int* hpix, int2* cpix2, int* winner,
                                             float* mcompE, float4* splatE4){
  int idx = blockIdx.x*256 + threadIdx.x;   // grid exactly 2N/256
  int b = idx / N_, pix = idx % N_;
  int y = pix / W_, x = pix % W_;
  mcompE[idx] = 0.f;
  splatE4[idx] = make_float4(0.f,0.f,0.f,0.f);
  float sF = clampScale(scal[2+b]);
  const float* fb = feat + (size_t)b*3*N_;
  // exact reference eval order, no FMA contraction (coords are integer-binned)
  float R  = __fmul_rn(__fdiv_rn(fb[pix],      sF), 255.0f);
  float G  = __fmul_rn(__fdiv_rn(fb[N_+pix],   sF), 255.0f);
  float Bl = __fmul_rn(__fdiv_rn(fb[2*N_+pix], sF), 255.0f);
  float Y = __fadd_rn(__fadd_rn(__fadd_rn(__fmul_rn(0.299f,R),     __fmul_rn(0.587f,G)),  __fmul_rn(0.114f,Bl)), 0.0f);
  float U = __fadd_rn(__fadd_rn(__fadd_rn(__fmul_rn(-0.168736f,R), __fmul_rn(-0.331264f,G)), __fmul_rn(0.5f,Bl)), 128.0f);
  float V = __fadd_rn(__fadd_rn(__fadd_rn(__fmul_rn(0.5f,R),       __fmul_rn(-0.418688f,G)), __fmul_rn(-0.081312f,Bl)), 128.0f);
  int c[5];
  c[0] = (int)floorf(__fdiv_rn((float)x, 7.0f));
  c[1] = (int)floorf(__fdiv_rn((float)y, 7.0f));
  c[2] = (int)floorf(__fdiv_rn(Y, 8.0f));
  c[3] = (int)floorf(__fdiv_rn(U, 2.0f));
  c[4] = (int)floorf(__fdiv_rn(V, 2.0f));
  unsigned hh = 0;
  #pragma unroll
  for(int d=0;d<5;d++) hh += (unsigned)c[d]*(unsigned)prime(d);
  hh &= TMASK_;
  hpix[idx]=(int)hh;
  cpix2[idx]=make_int2(c[0] | (c[1]<<10) | (c[2]<<20), c[3] | (c[4]<<10));
  atomicMax(&winner[(size_t)b*T_+(int)hh], pix);   // last-writer (max pix) wins = XLA scatter
}

// --- atomic-free 3-phase compaction (k_cmpA's 2-address atomics cost 4ms; see R7) ---

__global__ __launch_bounds__(256) void k_cnt(const int* winner, int* bcnt){
  int t = blockIdx.x*256 + threadIdx.x;   // grid exactly 2T/256
  bool occ = winner[t] >= 0;
  __shared__ int wc[4];
  unsigned long long mk = __ballot(occ);
  int lane = threadIdx.x & 63, w = threadIdx.x >> 6;
  if(lane==0) wc[w] = __popcll(mk);
  __syncthreads();
  if(threadIdx.x==0) bcnt[blockIdx.x] = wc[0]+wc[1]+wc[2]+wc[3];
}

// single-pass scan of 8192 block counts: thread t owns 32 contiguous entries
// (threads 0..127 = batch 0, 128..255 = batch 1 — 4096 boundary = thread 128).
// Produces bit-identical boff/count to the old 32-chunk serial scan, ~6x fewer barriers.
__global__ __launch_bounds__(256) void k_scan(const int* bcnt, int* boff, int* count){
  __shared__ int ssum[256];
  int t = threadIdx.x;
  int base = t*32;
  int loc[32];
  int s=0;
  #pragma unroll
  for(int j=0;j<32;j++){ loc[j]=s; s+=bcnt[base+j]; }   // local exclusive prefixes
  int mys = s;
  ssum[t]=s;
  __syncthreads();
  // inclusive Hillis-Steele within each 128-thread half (halves = batches)
  for(int st=1; st<128; st<<=1){
    int add = ((t&127) >= st) ? ssum[t-st] : 0;
    __syncthreads();
    ssum[t] += add;
    __syncthreads();
  }
  int excl = ssum[t] - mys;     // batch-local exclusive prefix for this thread's span
  #pragma unroll
  for(int j=0;j<32;j++) boff[base+j] = excl + loc[j];
  if(t==127) count[0]=ssum[127];
  if(t==255) count[1]=ssum[255];
}

// writes (-1,-1) markers for unoccupied slots directly (replaces the 16MB cidx2 memset)
__global__ __launch_bounds__(256) void k_cmp(const int* winner, const int* boff,
                                             int2* cidx2, int* slot_of){
  int t = blockIdx.x*256 + threadIdx.x;   // grid exactly 2T/256
  int b = t / T_;
  int wn = winner[t];
  bool occ = wn >= 0;
  __shared__ int wc[4];
  unsigned long long mk = __ballot(occ);
  int lane = threadIdx.x & 63, w = threadIdx.x >> 6;
  if(lane==0) wc[w] = __popcll(mk);
  __syncthreads();
  int wpre = 0;
  for(int k2=0;k2<4;k2++) if(k2<w) wpre += wc[k2];
  if(occ){
    int li = boff[blockIdx.x] + wpre + __popcll(mk & ((1ull<<lane)-1ull));
    int gi = b*N_ + li;
    cidx2[t] = make_int2(gi, wn);
    slot_of[gi] = t - b*T_;    // local slot hh
  } else {
    cidx2[t] = make_int2(-1, -1);   // unoccupied marker (.y<0)
  }
}

// conf normalize + splat: winner plain-stores; non-winners (~10%) atomicAdd into extras
__global__ __launch_bounds__(256) void k_px3(int* hpix_gpix, const int2* cidx2, const float* confr,
                                             const float* scal, float* confout, const float* pred,
                                             float* mcomp, float4* splat4, float* mcompE, float* splatE){
  int idx = blockIdx.x*256 + threadIdx.x;   // grid exactly 2N/256
  int b = idx / N_, pix = idx % N_;
  int2 cw = cidx2[(size_t)b*T_ + hpix_gpix[idx]];
  int gi = cw.x;
  hpix_gpix[idx] = gi;
  float w = confr[idx] / fmaxf(scal[4], 1e-5f);
  confout[idx] = w;
  const float* pb = pred + (size_t)b*3*N_;
  float v0 = __fmul_rn(w, pb[pix]);
  float v1 = __fmul_rn(w, pb[N_+pix]);
  float v2 = __fmul_rn(w, pb[2*N_+pix]);
  if(cw.y == pix){
    splat4[gi] = make_float4(v0,v1,v2,w);
    mcomp[gi] = 1.0f;
  } else {
    float* s = splatE + 4*(size_t)gi;
    atomicAdd(s+0, v0);
    atomicAdd(s+1, v1);
    atomicAdd(s+2, v2);
    atomicAdd(s+3, w);
    atomicAdd(&mcompE[gi], 1.0f);
  }
}

// ---------------- solver kernels (proven r5 CG path) ----------------
// CG state packing: zp[2i] = {z0,z1,z2,mi}, zp[2i+1] = {p0,p1,p2,nv} — one 64B line
// per neighbor gather in k_Ap.

// fused: merge extras + neighbor-table build + first bisto iter (n0=1)
__global__ __launch_bounds__(256) void k_bisto0(const int* count, const int* slot_of,
                      const int2* cpix2, const int2* cidx2, int* nbr,
                      float* mcomp, const float* mcompE, float4* splat4, const float4* splatE4,
                      float* nd){
  int i = blockIdx.x*256 + threadIdx.x;     // grid exactly 2N/256
  int b = i / N_, li = i - b*N_;
  if(li >= count[b]) return;
  int hh = slot_of[i];
  const int2* c2b = cidx2 + (size_t)b*T_;
  int2 cself = c2b[hh];
  int2 cp = cpix2[(size_t)b*N_ + cself.y];
  float4 sp = splat4[i]; float4 se = splatE4[i];
  sp.x+=se.x; sp.y+=se.y; sp.z+=se.z; sp.w+=se.w;
  splat4[i]=sp;
  float mTot = mcomp[i] + mcompE[i];
  mcomp[i]=mTot;
  float bv = 10.f;
  #pragma unroll
  for(int j=0;j<10;j++){
    int d=j>>1; int off=(j&1)?1:-1;
    unsigned nh = ((unsigned)hh + (unsigned)(off*prime(d))) & TMASK_;
    int nb = -1;
    int2 cn2 = c2b[nh];
    if(cn2.y>=0){
      int2 cn = cpix2[(size_t)b*N_ + cn2.y];
      int e0 = cp.x + (d==0?off: d==1?off*(1<<10) : d==2?off*(1<<20) : 0);
      int e1 = cp.y + (d==3?off: d==4?off*(1<<10) : 0);
      if(cn.x==e0 && cn.y==e1) nb = cn2.x;
    }
    nbr[(size_t)j*(2*N_)+i]=nb;
    if(nb>=0) bv += 1.0f;
  }
  nd[i] = sqrtf(1.0f*mTot/(bv+1e-12f));
}

__global__ __launch_bounds__(256) void k_bisto(const int* count, const int* nbr,
                                               const float* ns, float* nd, const float* mc){
  int i = blockIdx.x*256 + threadIdx.x;
  int b = i / N_, li = i - b*N_;
  if(li >= count[b]) return;
  float nv = ns[i];
  float bv = 10.f*nv;
  #pragma unroll
  for(int j=0;j<10;j++){
    int nb = nbr[(size_t)j*(2*N_)+i];
    if(nb>=0) bv += ns[nb];
  }
  nd[i] = sqrtf(nv*mc[i]/(bv+1e-12f));
}

// fused mfinal + x0 + A(x0) + r0/z0/p0 + rz0 per-batch reduction
__global__ __launch_bounds__(256) void k_Ar0(const int* count, const int* nbr, const float* n,
                      const float4* splat4, float4* meta4, float4* x4, float4* rS, float4* zp0,
                      double* rz0){
  int i = blockIdx.x*256 + threadIdx.x;
  int b = i / N_, li = i - b*N_;
  double a0=0.0,a1=0.0,a2=0.0;
  if(li < count[b]){
    float4 vb4 = splat4[i];
    float wsi = vb4.w;
    float nv = n[i];
    float x0 = vb4.x/(wsi+1e-12f);
    float x1 = vb4.y/(wsi+1e-12f);
    float x2 = vb4.z/(wsi+1e-12f);
    float bv = 10.f*nv;
    float s0=10.f*(nv*x0), s1=10.f*(nv*x1), s2=10.f*(nv*x2);
    #pragma unroll
    for(int j=0;j<10;j++){
      int nb = nbr[(size_t)j*(2*N_)+i];
      if(nb>=0){
        float4 vbn = splat4[nb];
        float nn = n[nb];
        bv += nn;
        s0 += nn*(vbn.x/(vbn.w+1e-12f));
        s1 += nn*(vbn.y/(vbn.w+1e-12f));
        s2 += nn*(vbn.z/(vbn.w+1e-12f));
      }
    }
    float mfin = nv*bv;
    float Ad = fmaxf(200.0f*(mfin - 10.f*nv*nv) + wsi, 1e-5f);
    float mi = 1.0f/Ad;
    float A0 = 200.f*(mfin*x0 - nv*s0) + wsi*x0;
    float A1 = 200.f*(mfin*x1 - nv*s1) + wsi*x1;
    float A2 = 200.f*(mfin*x2 - nv*s2) + wsi*x2;
    float r0v = vb4.x-A0, r1v = vb4.y-A1, r2v = vb4.z-A2;
    float z0=mi*r0v, z1=mi*r1v, z2=mi*r2v;
    meta4[i]=make_float4(nv,mfin,wsi,mi);
    x4[i]=make_float4(x0,x1,x2,0.f);
    rS[i]=make_float4(r0v,r1v,r2v,mi);
    zp0[2*(size_t)i]   = make_float4(z0,z1,z2,mi);
    zp0[2*(size_t)i+1] = make_float4(z0,z1,z2,nv);   // p0 = z0
    a0=(double)r0v*z0; a1=(double)r1v*z1; a2=(double)r2v*z2;
  }
  a0=blockReduceD(a0); a1=blockReduceD(a1); a2=blockReduceD(a2);
  if(threadIdx.x==0){
    double* base = rz0 + b*RZB_;
    redAdd(base,0,a0); redAdd(base,1,a1); redAdd(base,2,a2);
  }
}

// fused p-update + A: p = z + beta*pOld; gathers one 64B {z,p} line per neighbor.
// beta computed once per block (thread 0).
__global__ __launch_bounds__(256) void k_Ap(const int* count, const int* nbr, const float4* meta4,
                     const float4* __restrict__ zpCur, float4* __restrict__ zpNext, float4* Ap4,
                     const double* bNum, const double* bDen, int bstr, double* pAp){
  int i = blockIdx.x*256 + threadIdx.x;
  int b = (blockIdx.x*256) / N_;      // blocks never span batches
  int li = i - b*N_;
  __shared__ float sbe[3];
  if(threadIdx.x==0){
    if(bstr==0){ sbe[0]=0.f; sbe[1]=0.f; sbe[2]=0.f; }
    else{
      const double* nB_ = bNum + b*bstr;
      const double* dB_ = bDen + b*bstr;
      #pragma unroll
      for(int c=0;c<3;c++) sbe[c] = redSum(nB_,c) / (redSum(dB_,c)+1e-12f);
    }
  }
  __syncthreads();
  float be0=sbe[0], be1=sbe[1], be2=sbe[2];
  double a0=0.0,a1=0.0,a2=0.0;
  if(li < count[b]){
    float4 mt = meta4[i];
    float nv = mt.x, mfin = mt.y, wsi = mt.z;
    float4 zs = zpCur[2*(size_t)i];
    float4 ps = zpCur[2*(size_t)i+1];
    float p0 = zs.x + be0*ps.x;
    float p1 = zs.y + be1*ps.y;
    float p2 = zs.z + be2*ps.z;
    float s0=10.f*(nv*p0), s1=10.f*(nv*p1), s2=10.f*(nv*p2);
    #pragma unroll
    for(int j=0;j<10;j++){
      int nb = nbr[(size_t)j*(2*N_)+i];
      if(nb>=0){
        float4 zn = zpCur[2*(size_t)nb];
        float4 pn = zpCur[2*(size_t)nb+1];
        float nn = pn.w;
        s0 += nn*(zn.x + be0*pn.x);
        s1 += nn*(zn.y + be1*pn.y);
        s2 += nn*(zn.z + be2*pn.z);
      }
    }
    float A0 = 200.f*(mfin*p0 - nv*s0) + wsi*p0;
    float A1 = 200.f*(mfin*p1 - nv*s1) + wsi*p1;
    float A2 = 200.f*(mfin*p2 - nv*s2) + wsi*p2;
    zpNext[2*(size_t)i+1]=make_float4(p0,p1,p2,nv);
    Ap4[i]=make_float4(A0,A1,A2,0.f);
    a0=(double)p0*A0; a1=(double)p1*A1; a2=(double)p2*A2;
  }
  a0=blockReduceD(a0); a1=blockReduceD(a1); a2=blockReduceD(a2);
  if(threadIdx.x==0){
    double* base = pAp + b*PAPB_;
    redAdd(base,0,a0); redAdd(base,1,a1); redAdd(base,2,a2);
  }
}

// x/r update + z for next iter; alpha computed once per block (thread 0)
__global__ __launch_bounds__(256) void k_upd1(const int* count, float4* x4, float4* rS,
                       const float4* __restrict__ zpNext_p, float4* __restrict__ zpNext_z,
                       const float4* Ap4,
                       const double* rzCur, const double* pApC, double* rzNew, int doRz){
  int i = blockIdx.x*256 + threadIdx.x;
  int b = (blockIdx.x*256) / N_;
  int li = i - b*N_;
  __shared__ float sal[3];
  if(threadIdx.x==0){
    const double* rc = rzCur + b*RZB_;
    const double* pc = pApC  + b*PAPB_;
    #pragma unroll
    for(int c=0;c<3;c++) sal[c] = redSum(rc,c) / (redSum(pc,c)+1e-12f);
  }
  __syncthreads();
  float al0=sal[0], al1=sal[1], al2=sal[2];
  double a0=0.0,a1=0.0,a2=0.0;
  if(li < count[b]){
    float4 xv = x4[i];
    float4 rv = rS[i];
    float4 pv = zpNext_p[2*(size_t)i+1];
    float4 av = Ap4[i];
    float mi = rv.w;
    float x0=xv.x+al0*pv.x, x1=xv.y+al1*pv.y, x2=xv.z+al2*pv.z;
    float r0v=rv.x-al0*av.x, r1v=rv.y-al1*av.y, r2v=rv.z-al2*av.z;
    float z0=mi*r0v, z1=mi*r1v, z2=mi*r2v;
    x4[i]=make_float4(x0,x1,x2,0.f);
    rS[i]=make_float4(r0v,r1v,r2v,mi);
    zpNext_z[2*(size_t)i]=make_float4(z0,z1,z2,mi);
    a0=(double)r0v*z0; a1=(double)r1v*z1; a2=(double)r2v*z2;
  }
  if(doRz){
    a0=blockReduceD(a0); a1=blockReduceD(a1); a2=blockReduceD(a2);
    if(threadIdx.x==0){
      double* base = rzNew + b*RZB_;
      redAdd(base,0,a0); redAdd(base,1,a1); redAdd(base,2,a2);
    }
  }
}

__global__ __launch_bounds__(256) void k_out(const float4* x4, const int* gpix, float* out){
  int idx = blockIdx.x*256 + threadIdx.x;   // grid exactly 2N/256
  int b = idx / N_, pix = idx % N_;
  float4 xv = x4[gpix[idx]];
  out[((size_t)(b*3+0))*N_+pix] = xv.x;
  out[((size_t)(b*3+1))*N_+pix] = xv.y;
  out[((size_t)(b*3+2))*N_+pix] = xv.z;
}

// ---------------- host launcher ----------------

extern "C" void kernel_launch(void* const* d_in, const int* in_sizes, int n_in,
                              void* d_out, int out_size, void* d_ws, size_t ws_size,
                              hipStream_t stream){
  const float* image=(const float*)d_in[0];
  const float* feature=(const float*)d_in[1];
  const float* pred=(const float*)d_in[2];
  const float* w1=(const float*)d_in[3];  const float* b1=(const float*)d_in[4];
  const float* g1=(const float*)d_in[5];  const float* be1=(const float*)d_in[6];
  const float* w2=(const float*)d_in[7];  const float* b2=(const float*)d_in[8];
  const float* g2=(const float*)d_in[9];  const float* be2=(const float*)d_in[10];
  const float* wd1=(const float*)d_in[11];const float* bd1=(const float*)d_in[12];
  const float* gd1=(const float*)d_in[13];const float* bed1=(const float*)d_in[14];
  const float* wd2=(const float*)d_in[15];const float* bd2=(const float*)d_in[16];
  const float* gd2=(const float*)d_in[17];const float* bed2=(const float*)d_in[18];
  const float* wf=(const float*)d_in[19]; const float* bf=(const float*)d_in[20];
  float* outp=(float*)d_out;                          // (B,3,H,W)
  float* confout = outp + (size_t)B_*3*N_;            // (B,1,H,W)

  char* wsb=(char*)d_ws;
  float* scal=(float*)wsb;                  // [0..1] imgmax, [2..3] featmax, [4] confmax
  int* count=(int*)(wsb+256);               // count[2]
  double* scalD=(double*)(wsb+4096);        // 12608 doubles (see layout defines)
  double* zeroD = scalD;
  auto rzArr  = [&](int it)->double*{ return scalD + RZ0_  + it*192; };   // batch stride RZB_
  auto pApArr = [&](int it)->double*{ return scalD + PAP0_ + it*192; };   // batch stride PAPB_
  auto gnAcc  = [&](int L)->double*{ return scalD + GN0_ + L*512; };

  size_t off = 131072;
  auto alloc=[&](size_t bytes)->char*{ char* pp=wsb+off; off=(off+bytes+255)&~(size_t)255; return pp; };
  const size_t ALLOC0 = off;

  // CNN region (dead once conf is in confr; bilateral region overlaps it)
  float* x1   =(float*)alloc((size_t)B_*16*192*256*4);
  float* x1n  =(float*)alloc((size_t)B_*16*192*256*4);
  float* x2   =(float*)alloc((size_t)B_*16*96*128*4);
  float* x2n  =(float*)alloc((size_t)B_*16*96*128*4);
  float* dx1  =(float*)alloc((size_t)B_*16*96*128*4);
  float* dx1r =(float*)alloc((size_t)B_*16*192*256*4);
  float* dx2  =(float*)alloc((size_t)B_*16*192*256*4);
  float* dx2r =(float*)alloc((size_t)B_*16*N_*4);

  // bilateral region (reset offset: CNN buffers dead before the solver memsets/writes)
  off = ALLOC0;
  int*    winner =(int*)   alloc((size_t)2*T_*4);
  int2*   cidx2  =(int2*)  alloc((size_t)2*T_*8);
  int*    hpix   =(int*)   alloc((size_t)2*N_*4);    // becomes gpix after k_px3
  int2*   cpix2  =(int2*)  alloc((size_t)2*N_*8);
  int*    slot_of=(int*)   alloc((size_t)2*N_*4);
  int*    nbr    =(int*)   alloc((size_t)2*N_*10*4);
  float*  mcomp  =(float*) alloc((size_t)2*N_*4);
  float4* splat4 =(float4*)alloc((size_t)2*N_*16);
  float*  mcompE =(float*) alloc((size_t)2*N_*4);
  float*  splatE =(float*) alloc((size_t)2*N_*16);
  float*  nA     =(float*) alloc((size_t)2*N_*4);
  float*  nB     =(float*) alloc((size_t)2*N_*4);
  float4* meta4  =(float4*)alloc((size_t)2*N_*16);
  float4* x4     =(float4*)alloc((size_t)2*N_*16);
  float4* rS     =(float4*)alloc((size_t)2*N_*16);
  float4* zpA4   =(float4*)alloc((size_t)2*N_*32);   // {z,p} interleaved
  float4* zpB4   =(float4*)alloc((size_t)2*N_*32);
  int*    bcnt   =(int*)   alloc((size_t)G2T_*4);
  int*    boff   =(int*)   alloc((size_t)G2T_*4);
  float4* Ap4    = splat4;        // alias: splat4 dead after k_Ar0
  float*  confr  = (float*)zpB4;  // alias: zpB first written in k_Ap it=0; confr dead after px3

  dim3 blk(256);

  // ---- init scalars (scal, count, scalD) ----
  hipMemsetAsync(wsb, 0, 4096 + 12608*8, stream);

  // ---- CNN ----
  k_maxes<<<128,blk,0,stream>>>((const float4*)image,(const float4*)feature,scal);

  // conv1: OCSPLIT=4 -> 1536 blocks (6/CU); per-tap scale now a multiply (rsA hoisted)
  k_convT<true,3,3,4,2,true,384,512,192,256,4><<<4*((B_*192*256)/256),blk,0,stream>>>(
      image,pred,w1,b1,x1,gnAcc(0),scal);
  k_gnrelu<12288><<<(B_*16*12288)/256,blk,0,stream>>>((const float4*)x1,(float4*)x1n,gnAcc(0),g1,be1);
  // conv2: OCSPLIT=8 -> 768 blocks
  k_convT<false,16,0,4,2,true,192,256,96,128,8><<<8*((B_*96*128)/256),blk,0,stream>>>(
      x1n,x1n,w2,b2,x2,gnAcc(1),scal);
  k_gnrelu<3072><<<(B_*16*3072)/256,blk,0,stream>>>((const float4*)x2,(float4*)x2n,gnAcc(1),g2,be2);
  // conv3: OCSPLIT=8 -> 768 blocks
  k_convT<false,16,0,3,1,false,96,128,96,128,8><<<8*((B_*96*128)/256),blk,0,stream>>>(
      x2n,x2n,wd1,bd1,dx1,gnAcc(2),scal);
  k_resize2x<96,128><<<(B_*16*96*128)/256,blk,0,stream>>>(dx1, dx1r, gnAcc(2), gd1, bed1);
  // conv4 (wd2): OCSPLIT=4 -> 1536 blocks (6/CU)
  k_convT<false,16,16,3,1,false,192,256,192,256,4><<<4*((B_*192*256)/256),blk,0,stream>>>(
      dx1r,x1n,wd2,bd2,dx2,gnAcc(3),scal);
  k_resize2x<192,256><<<(B_*16*192*256)/256,blk,0,stream>>>(dx2, dx2r, gnAcc(3), gd2, bed2);

  k_conv5<<<(B_*(N_/2))/256,blk,0,stream>>>(dx2r, wf, bf, confr, scal);

  // ---- bilateral solver setup ----
  hipMemsetAsync(winner, 0xFF, (size_t)2*T_*4, stream);                      // winner = -1
  k_px1<<<G2N_,blk,0,stream>>>(feature,scal,hpix,cpix2,winner,mcompE,(float4*)splatE);
  k_cnt<<<G2T_,blk,0,stream>>>(winner,bcnt);
  k_scan<<<1,blk,0,stream>>>(bcnt,boff,count);
  k_cmp<<<G2T_,blk,0,stream>>>(winner,boff,cidx2,slot_of);
  k_px3<<<G2N_,blk,0,stream>>>(hpix,cidx2,confr,scal,confout,pred,mcomp,splat4,mcompE,splatE);

  // ---- bistochastization: fused extras-merge + nbr-build + it0, then 9 more ----
  k_bisto0<<<G2N_,blk,0,stream>>>(count,slot_of,cpix2,cidx2,nbr,mcomp,mcompE,splat4,(const float4*)splatE,nA);
  for(int it=1; it<10; ++it){
    float* src = (it&1) ? nA : nB;
    float* dst = (it&1) ? nB : nA;
    k_bisto<<<G2N_,blk,0,stream>>>(count,nbr,src,dst,mcomp);
  }
  float* nfin = nB;   // it9 (odd) wrote nB

  k_Ar0<<<G2N_,blk,0,stream>>>(count,nbr,nfin,splat4,meta4,x4,rS,zpA4,rzArr(0));

  float4* zp[2]={zpA4,zpB4};
  for(int it=0; it<12; ++it){
    float4* zpCur  = zp[it&1];
    float4* zpNext = zp[(it+1)&1];
    const double* bN = (it==0) ? zeroD : rzArr(it);
    const double* bD = (it==0) ? zeroD : rzArr(it-1);
    int bstr = (it==0) ? 0 : RZB_;
    k_Ap<<<G2N_,blk,0,stream>>>(count,nbr,meta4,zpCur,zpNext,Ap4,bN,bD,bstr,pApArr(it));
    k_upd1<<<G2N_,blk,0,stream>>>(count,x4,rS,zpNext,zpNext,Ap4,rzArr(it),pApArr(it),rzArr(it+1),(it<11)?1:0);
  }
  k_out<<<G2N_,blk,0,stream>>>(x4,hpix,outp);

  (void)in_sizes; (void)n_in; (void)out_size; (void)ws_size;
}